// Round 1
// baseline (817.441 us; speedup 1.0000x reference)
//
#include <hip/hip_runtime.h>
#include <hip/hip_bf16.h>

#define NG 64          // number of graphs
#define FLAT 2904      // FC output width
#define K128 128       // inner dim for both GEMMs

// ---------------------------------------------------------------- utilities
__device__ __forceinline__ float4 ld4(const float* p) { return *(const float4*)p; }
__device__ __forceinline__ void st4(float* p, float4 v) { *(float4*)p = v; }

// ------------------------------------------------- degree + in-degree hist
__global__ void k_deg_hist(const int* __restrict__ col, const float* __restrict__ ew,
                           float* __restrict__ deg, int* __restrict__ hist, int E) {
    int e = blockIdx.x * blockDim.x + threadIdx.x;
    if (e < E) {
        int c = col[e];
        atomicAdd(&deg[c], ew[e]);
        atomicAdd(&hist[c], 1);
    }
}

// deg -> dis = rsqrt(deg + 1)   (self-loop weight 1, deg always > 0)
__global__ void k_dis(float* __restrict__ deg, int N) {
    int v = blockIdx.x * blockDim.x + threadIdx.x;
    if (v < N) deg[v] = rsqrtf(deg[v] + 1.0f);
}

// ------------------------------------------------- single-block exclusive scan
__global__ __launch_bounds__(1024) void k_scan(const int* __restrict__ hist,
                                               int* __restrict__ rs,
                                               int* __restrict__ cursor, int N) {
    __shared__ int part[1024];
    int tid = threadIdx.x;
    int per = (N + 1023) / 1024;
    int start = tid * per;
    int end   = start + per; if (end > N) end = N;
    int sum = 0;
    for (int i = start; i < end; i++) sum += hist[i];
    part[tid] = sum;
    __syncthreads();
    for (int off = 1; off < 1024; off <<= 1) {
        int v = (tid >= off) ? part[tid - off] : 0;
        __syncthreads();
        part[tid] += v;
        __syncthreads();
    }
    int run = (tid > 0) ? part[tid - 1] : 0;
    for (int i = start; i < end; i++) {
        rs[i] = run; cursor[i] = run;
        run += hist[i];
    }
    if (tid == 1023) rs[N] = part[1023];
}

// ------------------------------------------------- scatter edge ids + norm
__global__ void k_scatter(const int* __restrict__ row, const int* __restrict__ col,
                          const float* __restrict__ ew, const float* __restrict__ dis,
                          int* __restrict__ cursor, int* __restrict__ perm,
                          float* __restrict__ norm, int E) {
    int e = blockIdx.x * blockDim.x + threadIdx.x;
    if (e < E) {
        int c = col[e], r = row[e];
        norm[e] = dis[r] * ew[e] * dis[c];
        int pos = atomicAdd(&cursor[c], 1);
        perm[pos] = e;
    }
}

// ------------------------------------------------- fp32 GEMM: out[M,NCOL] = A[M,128] @ W[128,NCOL]
template <int NCOL>
__global__ __launch_bounds__(256) void k_gemm(const float* __restrict__ A,
                                              const float* __restrict__ W,
                                              float* __restrict__ out, int M) {
    constexpr int JG  = NCOL / 4;   // threads per row
    constexpr int RPB = 256 / JG;   // rows per block
    int r  = blockIdx.x * RPB + threadIdx.x / JG;
    int j4 = (threadIdx.x % JG) * 4;
    if (r >= M) return;
    const float* a = A + (size_t)r * K128;
    float4 acc = make_float4(0.f, 0.f, 0.f, 0.f);
#pragma unroll 8
    for (int k = 0; k < K128; k++) {
        float av = a[k];
        float4 w = ld4(W + k * NCOL + j4);
        acc.x += av * w.x; acc.y += av * w.y; acc.z += av * w.z; acc.w += av * w.w;
    }
    st4(out + (size_t)r * NCOL + j4, acc);
}

// ------------------------------------------------- CSR gather aggregation + self + bias + relu
template <int F>
__global__ __launch_bounds__(256) void k_agg(const float* __restrict__ xw,
                                             const float* __restrict__ dis,
                                             const float* __restrict__ norm,
                                             const int* __restrict__ row,
                                             const int* __restrict__ rs,
                                             const int* __restrict__ perm,
                                             const float* __restrict__ bias,
                                             float* __restrict__ out, int N) {
    constexpr int TPN = F / 4;     // threads per node
    constexpr int NPB = 256 / TPN; // nodes per block
    int node = blockIdx.x * NPB + threadIdx.x / TPN;
    int j4   = (threadIdx.x % TPN) * 4;
    if (node >= N) return;
    float dv = dis[node];
    float sw = dv * dv;                       // self-loop coeff = 1/deg
    float4 self = ld4(xw + (size_t)node * F + j4);
    float4 bv   = ld4(bias + j4);
    float4 acc;
    acc.x = self.x * sw + bv.x;
    acc.y = self.y * sw + bv.y;
    acc.z = self.z * sw + bv.z;
    acc.w = self.w * sw + bv.w;
    int s = rs[node], e = rs[node + 1];
    for (int j = s; j < e; j++) {
        int ed   = perm[j];
        float nm = norm[ed];
        int r    = row[ed];
        float4 v = ld4(xw + (size_t)r * F + j4);
        acc.x += nm * v.x; acc.y += nm * v.y; acc.z += nm * v.z; acc.w += nm * v.w;
    }
    acc.x = fmaxf(acc.x, 0.f); acc.y = fmaxf(acc.y, 0.f);
    acc.z = fmaxf(acc.z, 0.f); acc.w = fmaxf(acc.w, 0.f);
    st4(out + (size_t)node * F + j4, acc);
}

// ------------------------------------------------- mean-pool accumulate (atomics)
__global__ __launch_bounds__(256) void k_pool(const float* __restrict__ h,
                                              const int* __restrict__ batch,
                                              float* __restrict__ g, int* __restrict__ gcnt,
                                              int N) {
    int node = blockIdx.x * 4 + threadIdx.x / 64;
    int f    = threadIdx.x % 64;
    if (node >= N) return;
    int b = batch[node];
    atomicAdd(&g[b * 64 + f], h[(size_t)node * 64 + f]);
    if (f == 0) atomicAdd(&gcnt[b], 1);
}

// ------------------------------------------------- FC: out[NG,FLAT] = (g/cnt) @ Wfc + bfc
__global__ __launch_bounds__(256) void k_fc(const float* __restrict__ g,
                                            const int* __restrict__ gcnt,
                                            const float* __restrict__ Wfc,
                                            const float* __restrict__ bfc,
                                            float* __restrict__ out) {
    __shared__ float gs[64];
    int i = blockIdx.y;
    int j = blockIdx.x * blockDim.x + threadIdx.x;
    if (threadIdx.x < 64) {
        float c = (float)gcnt[i];
        gs[threadIdx.x] = g[i * 64 + threadIdx.x] / fmaxf(c, 1.0f);
    }
    __syncthreads();
    if (j >= FLAT) return;
    float acc = bfc[j];
#pragma unroll 8
    for (int k = 0; k < 64; k++) acc += gs[k] * Wfc[k * FLAT + j];
    out[(size_t)i * FLAT + j] = acc;
}

// ================================================================ launcher
extern "C" void kernel_launch(void* const* d_in, const int* in_sizes, int n_in,
                              void* d_out, int out_size, void* d_ws, size_t ws_size,
                              hipStream_t stream) {
    const float* x    = (const float*)d_in[0];
    const int*   ei   = (const int*)d_in[1];
    const float* ew   = (const float*)d_in[2];
    const int*   batch= (const int*)d_in[3];
    const float* W1   = (const float*)d_in[4];
    const float* b1   = (const float*)d_in[5];
    const float* W2   = (const float*)d_in[6];
    const float* b2   = (const float*)d_in[7];
    const float* Wfc  = (const float*)d_in[8];
    const float* bfc  = (const float*)d_in[9];
    float* out = (float*)d_out;

    const int N = in_sizes[0] / K128;   // 40000
    const int E = in_sizes[2];          // 640000
    const int* row = ei;
    const int* col = ei + E;

    // ---- workspace carve (256B aligned)
    char* p = (char*)d_ws;
    auto alloc = [&](size_t bytes) -> void* {
        void* r = (void*)p;
        p += (bytes + 255) & ~(size_t)255;
        return r;
    };
    float* deg   = (float*)alloc((size_t)N * 4);        // becomes dis in-place
    int*   hist  = (int*)  alloc((size_t)N * 4);
    int*   rs    = (int*)  alloc((size_t)(N + 1) * 4);
    int*   cursor= (int*)  alloc((size_t)N * 4);
    int*   perm  = (int*)  alloc((size_t)E * 4);
    float* norm  = (float*)alloc((size_t)E * 4);
    float* xw1   = (float*)alloc((size_t)N * 128 * 4);
    float* h1    = (float*)alloc((size_t)N * 128 * 4);
    float* xw2   = (float*)alloc((size_t)N * 64 * 4);
    float* h2    = (float*)alloc((size_t)N * 64 * 4);
    float* g     = (float*)alloc(64 * 64 * 4);
    int*   gcnt  = (int*)  alloc(64 * 4);

    // ---- zero accumulators (ws is poisoned 0xAA before every launch)
    hipMemsetAsync(deg,  0, (size_t)N * 4, stream);
    hipMemsetAsync(hist, 0, (size_t)N * 4, stream);
    hipMemsetAsync(g,    0, 64 * 64 * 4,   stream);
    hipMemsetAsync(gcnt, 0, 64 * 4,        stream);

    // ---- graph preprocessing (shared by both layers)
    k_deg_hist<<<(E + 255) / 256, 256, 0, stream>>>(col, ew, deg, hist, E);
    k_dis<<<(N + 255) / 256, 256, 0, stream>>>(deg, N);
    k_scan<<<1, 1024, 0, stream>>>(hist, rs, cursor, N);
    k_scatter<<<(E + 255) / 256, 256, 0, stream>>>(row, col, ew, deg, cursor, perm, norm, E);

    // ---- layer 1
    k_gemm<128><<<(N + 7) / 8, 256, 0, stream>>>(x, W1, xw1, N);
    k_agg<128><<<(N + 7) / 8, 256, 0, stream>>>(xw1, deg, norm, row, rs, perm, b1, h1, N);

    // ---- layer 2
    k_gemm<64><<<(N + 15) / 16, 256, 0, stream>>>(h1, W2, xw2, N);
    k_agg<64><<<(N + 15) / 16, 256, 0, stream>>>(xw2, deg, norm, row, rs, perm, b2, h2, N);

    // ---- pool + fc
    k_pool<<<(N + 3) / 4, 256, 0, stream>>>(h2, batch, g, gcnt, N);
    dim3 fcg((FLAT + 255) / 256, NG);
    k_fc<<<fcg, 256, 0, stream>>>(g, gcnt, Wfc, bfc, out);
}

// Round 2
// 568.864 us; speedup vs baseline: 1.4370x; 1.4370x over previous
//
#include <hip/hip_runtime.h>
#include <hip/hip_bf16.h>

#define NG 64          // number of graphs
#define FLAT 2904      // FC output width
#define K128 128       // inner dim for both GEMMs

// ---------------------------------------------------------------- utilities
__device__ __forceinline__ float4 ld4(const float* p) { return *(const float4*)p; }
__device__ __forceinline__ void st4(float* p, float4 v) { *(float4*)p = v; }

// ------------------------------------------------- degree + in-degree hist
__global__ void k_deg_hist(const int* __restrict__ col, const float* __restrict__ ew,
                           float* __restrict__ deg, int* __restrict__ hist, int E) {
    int e = blockIdx.x * blockDim.x + threadIdx.x;
    if (e < E) {
        int c = col[e];
        atomicAdd(&deg[c], ew[e]);
        atomicAdd(&hist[c], 1);
    }
}

// deg -> dis = rsqrt(deg + 1)   (self-loop weight 1, deg always > 0)
__global__ void k_dis(float* __restrict__ deg, int N) {
    int v = blockIdx.x * blockDim.x + threadIdx.x;
    if (v < N) deg[v] = rsqrtf(deg[v] + 1.0f);
}

// ------------------------------------------------- single-block exclusive scan
__global__ __launch_bounds__(1024) void k_scan(const int* __restrict__ hist,
                                               int* __restrict__ rs,
                                               int* __restrict__ cursor, int N) {
    __shared__ int part[1024];
    int tid = threadIdx.x;
    int per = (N + 1023) / 1024;
    int start = tid * per;
    int end   = start + per; if (end > N) end = N;
    int sum = 0;
    for (int i = start; i < end; i++) sum += hist[i];
    part[tid] = sum;
    __syncthreads();
    for (int off = 1; off < 1024; off <<= 1) {
        int v = (tid >= off) ? part[tid - off] : 0;
        __syncthreads();
        part[tid] += v;
        __syncthreads();
    }
    int run = (tid > 0) ? part[tid - 1] : 0;
    for (int i = start; i < end; i++) {
        rs[i] = run; cursor[i] = run;
        run += hist[i];
    }
    if (tid == 1023) rs[N] = part[1023];
}

// ------------------------------------------------- scatter edge ids + norm
__global__ void k_scatter(const int* __restrict__ row, const int* __restrict__ col,
                          const float* __restrict__ ew, const float* __restrict__ dis,
                          int* __restrict__ cursor, int* __restrict__ perm,
                          float* __restrict__ norm, int E) {
    int e = blockIdx.x * blockDim.x + threadIdx.x;
    if (e < E) {
        int c = col[e], r = row[e];
        norm[e] = dis[r] * ew[e] * dis[c];
        int pos = atomicAdd(&cursor[c], 1);
        perm[pos] = e;
    }
}

// ------------------------------------------------- fp32 GEMM: out[M,NCOL] = A[M,128] @ W[128,NCOL]
template <int NCOL>
__global__ __launch_bounds__(256) void k_gemm(const float* __restrict__ A,
                                              const float* __restrict__ W,
                                              float* __restrict__ out, int M) {
    constexpr int JG  = NCOL / 4;   // threads per row
    constexpr int RPB = 256 / JG;   // rows per block
    int r  = blockIdx.x * RPB + threadIdx.x / JG;
    int j4 = (threadIdx.x % JG) * 4;
    if (r >= M) return;
    const float* a = A + (size_t)r * K128;
    float4 acc = make_float4(0.f, 0.f, 0.f, 0.f);
#pragma unroll 8
    for (int k = 0; k < K128; k++) {
        float av = a[k];
        float4 w = ld4(W + k * NCOL + j4);
        acc.x += av * w.x; acc.y += av * w.y; acc.z += av * w.z; acc.w += av * w.w;
    }
    st4(out + (size_t)r * NCOL + j4, acc);
}

// ------------------------------------------------- CSR gather aggregation + self + bias + relu
template <int F>
__global__ __launch_bounds__(256) void k_agg(const float* __restrict__ xw,
                                             const float* __restrict__ dis,
                                             const float* __restrict__ norm,
                                             const int* __restrict__ row,
                                             const int* __restrict__ rs,
                                             const int* __restrict__ perm,
                                             const float* __restrict__ bias,
                                             float* __restrict__ out, int N) {
    constexpr int TPN = F / 4;     // threads per node
    constexpr int NPB = 256 / TPN; // nodes per block
    int node = blockIdx.x * NPB + threadIdx.x / TPN;
    int j4   = (threadIdx.x % TPN) * 4;
    if (node >= N) return;
    float dv = dis[node];
    float sw = dv * dv;                       // self-loop coeff = 1/deg
    float4 self = ld4(xw + (size_t)node * F + j4);
    float4 bv   = ld4(bias + j4);
    float4 acc;
    acc.x = self.x * sw + bv.x;
    acc.y = self.y * sw + bv.y;
    acc.z = self.z * sw + bv.z;
    acc.w = self.w * sw + bv.w;
    int s = rs[node], e = rs[node + 1];
    for (int j = s; j < e; j++) {
        int ed   = perm[j];
        float nm = norm[ed];
        int r    = row[ed];
        float4 v = ld4(xw + (size_t)r * F + j4);
        acc.x += nm * v.x; acc.y += nm * v.y; acc.z += nm * v.z; acc.w += nm * v.w;
    }
    acc.x = fmaxf(acc.x, 0.f); acc.y = fmaxf(acc.y, 0.f);
    acc.z = fmaxf(acc.z, 0.f); acc.w = fmaxf(acc.w, 0.f);
    st4(out + (size_t)node * F + j4, acc);
}

// ------------------------------------------------- mean-pool accumulate
// batch is SORTED: register-accumulate per thread, flush one atomic per
// graph-id change. 256 nodes/block x 4 slices: ~2 graphs/block -> ~80K
// atomics total (was 2.56M onto 4096 addrs = 275us of serialized L2 atomics).
#define POOL_NODES 256
__global__ __launch_bounds__(256) void k_pool(const float* __restrict__ h,
                                              const int* __restrict__ batch,
                                              float* __restrict__ g, int* __restrict__ gcnt,
                                              int N) {
    int base  = blockIdx.x * POOL_NODES;
    int f     = threadIdx.x & 63;
    int slice = threadIdx.x >> 6;          // 0..3
    int lim   = base + POOL_NODES; if (lim > N) lim = N;
    float acc = 0.f;
    int cur = -1, cnt = 0;
    for (int i = base + slice; i < lim; i += 4) {
        int b = batch[i];
        if (b != cur) {
            if (cur >= 0) {
                atomicAdd(&g[cur * 64 + f], acc);
                if (f == 0) atomicAdd(&gcnt[cur], cnt);
            }
            cur = b; acc = 0.f; cnt = 0;
        }
        acc += h[(size_t)i * 64 + f];
        cnt++;
    }
    if (cur >= 0) {
        atomicAdd(&g[cur * 64 + f], acc);
        if (f == 0) atomicAdd(&gcnt[cur], cnt);
    }
}

// ------------------------------------------------- FC: out[NG,FLAT] = (g/cnt) @ Wfc + bfc
__global__ __launch_bounds__(256) void k_fc(const float* __restrict__ g,
                                            const int* __restrict__ gcnt,
                                            const float* __restrict__ Wfc,
                                            const float* __restrict__ bfc,
                                            float* __restrict__ out) {
    __shared__ float gs[64];
    int i = blockIdx.y;
    int j = blockIdx.x * blockDim.x + threadIdx.x;
    if (threadIdx.x < 64) {
        float c = (float)gcnt[i];
        gs[threadIdx.x] = g[i * 64 + threadIdx.x] / fmaxf(c, 1.0f);
    }
    __syncthreads();
    if (j >= FLAT) return;
    float acc = bfc[j];
#pragma unroll 8
    for (int k = 0; k < 64; k++) acc += gs[k] * Wfc[k * FLAT + j];
    out[(size_t)i * FLAT + j] = acc;
}

// ================================================================ launcher
extern "C" void kernel_launch(void* const* d_in, const int* in_sizes, int n_in,
                              void* d_out, int out_size, void* d_ws, size_t ws_size,
                              hipStream_t stream) {
    const float* x    = (const float*)d_in[0];
    const int*   ei   = (const int*)d_in[1];
    const float* ew   = (const float*)d_in[2];
    const int*   batch= (const int*)d_in[3];
    const float* W1   = (const float*)d_in[4];
    const float* b1   = (const float*)d_in[5];
    const float* W2   = (const float*)d_in[6];
    const float* b2   = (const float*)d_in[7];
    const float* Wfc  = (const float*)d_in[8];
    const float* bfc  = (const float*)d_in[9];
    float* out = (float*)d_out;

    const int N = in_sizes[0] / K128;   // 40000
    const int E = in_sizes[2];          // 640000
    const int* row = ei;
    const int* col = ei + E;

    // ---- workspace carve (256B aligned)
    char* p = (char*)d_ws;
    auto alloc = [&](size_t bytes) -> void* {
        void* r = (void*)p;
        p += (bytes + 255) & ~(size_t)255;
        return r;
    };
    float* deg   = (float*)alloc((size_t)N * 4);        // becomes dis in-place
    int*   hist  = (int*)  alloc((size_t)N * 4);
    int*   rs    = (int*)  alloc((size_t)(N + 1) * 4);
    int*   cursor= (int*)  alloc((size_t)N * 4);
    int*   perm  = (int*)  alloc((size_t)E * 4);
    float* norm  = (float*)alloc((size_t)E * 4);
    float* xw1   = (float*)alloc((size_t)N * 128 * 4);
    float* h1    = (float*)alloc((size_t)N * 128 * 4);
    float* xw2   = (float*)alloc((size_t)N * 64 * 4);
    float* h2    = (float*)alloc((size_t)N * 64 * 4);
    float* g     = (float*)alloc(64 * 64 * 4);
    int*   gcnt  = (int*)  alloc(64 * 4);

    // ---- zero accumulators (ws is poisoned 0xAA before every launch)
    hipMemsetAsync(deg,  0, (size_t)N * 4, stream);
    hipMemsetAsync(hist, 0, (size_t)N * 4, stream);
    hipMemsetAsync(g,    0, 64 * 64 * 4,   stream);
    hipMemsetAsync(gcnt, 0, 64 * 4,        stream);

    // ---- graph preprocessing (shared by both layers)
    k_deg_hist<<<(E + 255) / 256, 256, 0, stream>>>(col, ew, deg, hist, E);
    k_dis<<<(N + 255) / 256, 256, 0, stream>>>(deg, N);
    k_scan<<<1, 1024, 0, stream>>>(hist, rs, cursor, N);
    k_scatter<<<(E + 255) / 256, 256, 0, stream>>>(row, col, ew, deg, cursor, perm, norm, E);

    // ---- layer 1
    k_gemm<128><<<(N + 7) / 8, 256, 0, stream>>>(x, W1, xw1, N);
    k_agg<128><<<(N + 7) / 8, 256, 0, stream>>>(xw1, deg, norm, row, rs, perm, b1, h1, N);

    // ---- layer 2
    k_gemm<64><<<(N + 15) / 16, 256, 0, stream>>>(h1, W2, xw2, N);
    k_agg<64><<<(N + 15) / 16, 256, 0, stream>>>(xw2, deg, norm, row, rs, perm, b2, h2, N);

    // ---- pool + fc
    k_pool<<<(N + POOL_NODES - 1) / POOL_NODES, 256, 0, stream>>>(h2, batch, g, gcnt, N);
    dim3 fcg((FLAT + 255) / 256, NG);
    k_fc<<<fcg, 256, 0, stream>>>(g, gcnt, Wfc, bfc, out);
}

// Round 3
// 465.812 us; speedup vs baseline: 1.7549x; 1.2212x over previous
//
#include <hip/hip_runtime.h>
#include <hip/hip_bf16.h>

#define NG 64          // number of graphs
#define FLAT 2904      // FC output width
#define K128 128       // inner dim for both GEMMs

// ---------------------------------------------------------------- utilities
__device__ __forceinline__ float4 ld4(const float* p) { return *(const float4*)p; }
__device__ __forceinline__ void st4(float* p, float4 v) { *(float4*)p = v; }

// ------------------------------------------------- degree + in-degree hist
__global__ void k_deg_hist(const int* __restrict__ col, const float* __restrict__ ew,
                           float* __restrict__ deg, int* __restrict__ hist, int E) {
    int e = blockIdx.x * blockDim.x + threadIdx.x;
    if (e < E) {
        int c = col[e];
        atomicAdd(&deg[c], ew[e]);
        atomicAdd(&hist[c], 1);
    }
}

// deg -> dis = rsqrt(deg + 1)   (self-loop weight 1, deg always > 0)
__global__ void k_dis(float* __restrict__ deg, int N) {
    int v = blockIdx.x * blockDim.x + threadIdx.x;
    if (v < N) deg[v] = rsqrtf(deg[v] + 1.0f);
}

// ------------------------------------------------- single-block exclusive scan
__global__ __launch_bounds__(1024) void k_scan(const int* __restrict__ hist,
                                               int* __restrict__ rs,
                                               int* __restrict__ cursor, int N) {
    __shared__ int part[1024];
    int tid = threadIdx.x;
    int per = (N + 1023) / 1024;
    int start = tid * per;
    int end   = start + per; if (end > N) end = N;
    int sum = 0;
    for (int i = start; i < end; i++) sum += hist[i];
    part[tid] = sum;
    __syncthreads();
    for (int off = 1; off < 1024; off <<= 1) {
        int v = (tid >= off) ? part[tid - off] : 0;
        __syncthreads();
        part[tid] += v;
        __syncthreads();
    }
    int run = (tid > 0) ? part[tid - 1] : 0;
    for (int i = start; i < end; i++) {
        rs[i] = run; cursor[i] = run;
        run += hist[i];
    }
    if (tid == 1023) rs[N] = part[1023];
}

// ------------------------------------------------- scatter edge ids + norm
__global__ void k_scatter(const int* __restrict__ row, const int* __restrict__ col,
                          const float* __restrict__ ew, const float* __restrict__ dis,
                          int* __restrict__ cursor, int* __restrict__ perm,
                          float* __restrict__ norm, int E) {
    int e = blockIdx.x * blockDim.x + threadIdx.x;
    if (e < E) {
        int c = col[e], r = row[e];
        norm[e] = dis[r] * ew[e] * dis[c];
        int pos = atomicAdd(&cursor[c], 1);
        perm[pos] = e;
    }
}

// ------------------------------------------------- fp32 register-tiled GEMM
// out[M,NCOL] = A[M,128] @ W[128,NCOL].
// 256 thr/block; thread = (tx: NCOL/4 col-groups, ty: row-groups), 8 rows x 4
// cols = 32 acc regs. A-tile + W-chunk staged in LDS, K chunked by 32.
// A LDS stride 36 floats (144 B = 9*16 B): b128-aligned, rows land on
// rotating bank quads -> conflict-free ds_read_b128.
template <int NCOL>
__global__ __launch_bounds__(256) void k_gemm(const float* __restrict__ A,
                                              const float* __restrict__ W,
                                              float* __restrict__ out, int M) {
    constexpr int JG   = NCOL / 4;    // col groups (threads per row strip)
    constexpr int RG   = 256 / JG;    // row groups
    constexpr int RPT  = 8;           // rows per thread
    constexpr int ROWS = RG * RPT;    // rows per block (64 or 128)
    constexpr int KC   = 32;          // k chunk
    constexpr int AS   = KC + 4;      // A LDS stride (36 floats)

    __shared__ float As[ROWS * AS];
    __shared__ float Ws[KC * NCOL];

    int tid = threadIdx.x;
    int tx  = tid % JG;
    int ty  = tid / JG;
    int row0 = blockIdx.x * ROWS;

    float4 acc[RPT];
#pragma unroll
    for (int i = 0; i < RPT; i++) acc[i] = make_float4(0.f, 0.f, 0.f, 0.f);

    for (int kc = 0; kc < K128; kc += KC) {
        // ---- stage A tile: ROWS x 32 floats (coalesced float4 loads)
#pragma unroll
        for (int q = 0; q < ROWS * 8 / 256; q++) {
            int idx = tid + 256 * q;
            int r   = idx >> 3;        // 0..ROWS-1
            int f4  = (idx & 7) * 4;   // 0..28
            int gr  = row0 + r; if (gr >= M) gr = M - 1;
            float4 v = ld4(A + (size_t)gr * K128 + kc + f4);
            st4(&As[r * AS + f4], v);
        }
        // ---- stage W chunk: 32 x NCOL floats (fully coalesced, linear)
#pragma unroll
        for (int q = 0; q < KC * NCOL / 4 / 256; q++) {
            int idx = (tid + 256 * q) * 4;
            st4(&Ws[idx], ld4(W + (size_t)kc * NCOL + idx));
        }
        __syncthreads();

        // ---- compute: per 4-k group, 12 ds_read_b128 + 128 FMAs
#pragma unroll
        for (int k4 = 0; k4 < KC; k4 += 4) {
            float4 w0 = ld4(&Ws[(k4 + 0) * NCOL + tx * 4]);
            float4 w1 = ld4(&Ws[(k4 + 1) * NCOL + tx * 4]);
            float4 w2 = ld4(&Ws[(k4 + 2) * NCOL + tx * 4]);
            float4 w3 = ld4(&Ws[(k4 + 3) * NCOL + tx * 4]);
#pragma unroll
            for (int i = 0; i < RPT; i++) {
                float4 a = ld4(&As[(ty + RG * i) * AS + k4]);
                acc[i].x += a.x * w0.x; acc[i].y += a.x * w0.y;
                acc[i].z += a.x * w0.z; acc[i].w += a.x * w0.w;
                acc[i].x += a.y * w1.x; acc[i].y += a.y * w1.y;
                acc[i].z += a.y * w1.z; acc[i].w += a.y * w1.w;
                acc[i].x += a.z * w2.x; acc[i].y += a.z * w2.y;
                acc[i].z += a.z * w2.z; acc[i].w += a.z * w2.w;
                acc[i].x += a.w * w3.x; acc[i].y += a.w * w3.y;
                acc[i].z += a.w * w3.z; acc[i].w += a.w * w3.w;
            }
        }
        __syncthreads();
    }

#pragma unroll
    for (int i = 0; i < RPT; i++) {
        int r = row0 + ty + RG * i;
        if (r < M) st4(out + (size_t)r * NCOL + tx * 4, acc[i]);
    }
}

// ------------------------------------------------- CSR gather aggregation + self + bias + relu
template <int F>
__global__ __launch_bounds__(256) void k_agg(const float* __restrict__ xw,
                                             const float* __restrict__ dis,
                                             const float* __restrict__ norm,
                                             const int* __restrict__ row,
                                             const int* __restrict__ rs,
                                             const int* __restrict__ perm,
                                             const float* __restrict__ bias,
                                             float* __restrict__ out, int N) {
    constexpr int TPN = F / 4;     // threads per node
    constexpr int NPB = 256 / TPN; // nodes per block
    int node = blockIdx.x * NPB + threadIdx.x / TPN;
    int j4   = (threadIdx.x % TPN) * 4;
    if (node >= N) return;
    float dv = dis[node];
    float sw = dv * dv;                       // self-loop coeff = 1/deg
    float4 self = ld4(xw + (size_t)node * F + j4);
    float4 bv   = ld4(bias + j4);
    float4 acc;
    acc.x = self.x * sw + bv.x;
    acc.y = self.y * sw + bv.y;
    acc.z = self.z * sw + bv.z;
    acc.w = self.w * sw + bv.w;
    int s = rs[node], e = rs[node + 1];
    for (int j = s; j < e; j++) {
        int ed   = perm[j];
        float nm = norm[ed];
        int r    = row[ed];
        float4 v = ld4(xw + (size_t)r * F + j4);
        acc.x += nm * v.x; acc.y += nm * v.y; acc.z += nm * v.z; acc.w += nm * v.w;
    }
    acc.x = fmaxf(acc.x, 0.f); acc.y = fmaxf(acc.y, 0.f);
    acc.z = fmaxf(acc.z, 0.f); acc.w = fmaxf(acc.w, 0.f);
    st4(out + (size_t)node * F + j4, acc);
}

// ------------------------------------------------- mean-pool accumulate
// batch is SORTED: register-accumulate per thread, flush one atomic per
// graph-id change.
#define POOL_NODES 256
__global__ __launch_bounds__(256) void k_pool(const float* __restrict__ h,
                                              const int* __restrict__ batch,
                                              float* __restrict__ g, int* __restrict__ gcnt,
                                              int N) {
    int base  = blockIdx.x * POOL_NODES;
    int f     = threadIdx.x & 63;
    int slice = threadIdx.x >> 6;          // 0..3
    int lim   = base + POOL_NODES; if (lim > N) lim = N;
    float acc = 0.f;
    int cur = -1, cnt = 0;
    for (int i = base + slice; i < lim; i += 4) {
        int b = batch[i];
        if (b != cur) {
            if (cur >= 0) {
                atomicAdd(&g[cur * 64 + f], acc);
                if (f == 0) atomicAdd(&gcnt[cur], cnt);
            }
            cur = b; acc = 0.f; cnt = 0;
        }
        acc += h[(size_t)i * 64 + f];
        cnt++;
    }
    if (cur >= 0) {
        atomicAdd(&g[cur * 64 + f], acc);
        if (f == 0) atomicAdd(&gcnt[cur], cnt);
    }
}

// ------------------------------------------------- FC: out[NG,FLAT] = (g/cnt) @ Wfc + bfc
__global__ __launch_bounds__(256) void k_fc(const float* __restrict__ g,
                                            const int* __restrict__ gcnt,
                                            const float* __restrict__ Wfc,
                                            const float* __restrict__ bfc,
                                            float* __restrict__ out) {
    __shared__ float gs[64];
    int i = blockIdx.y;
    int j = blockIdx.x * blockDim.x + threadIdx.x;
    if (threadIdx.x < 64) {
        float c = (float)gcnt[i];
        gs[threadIdx.x] = g[i * 64 + threadIdx.x] / fmaxf(c, 1.0f);
    }
    __syncthreads();
    if (j >= FLAT) return;
    float acc = bfc[j];
#pragma unroll 8
    for (int k = 0; k < 64; k++) acc += gs[k] * Wfc[k * FLAT + j];
    out[(size_t)i * FLAT + j] = acc;
}

// ================================================================ launcher
extern "C" void kernel_launch(void* const* d_in, const int* in_sizes, int n_in,
                              void* d_out, int out_size, void* d_ws, size_t ws_size,
                              hipStream_t stream) {
    const float* x    = (const float*)d_in[0];
    const int*   ei   = (const int*)d_in[1];
    const float* ew   = (const float*)d_in[2];
    const int*   batch= (const int*)d_in[3];
    const float* W1   = (const float*)d_in[4];
    const float* b1   = (const float*)d_in[5];
    const float* W2   = (const float*)d_in[6];
    const float* b2   = (const float*)d_in[7];
    const float* Wfc  = (const float*)d_in[8];
    const float* bfc  = (const float*)d_in[9];
    float* out = (float*)d_out;

    const int N = in_sizes[0] / K128;   // 40000
    const int E = in_sizes[2];          // 640000
    const int* row = ei;
    const int* col = ei + E;

    // ---- workspace carve (256B aligned)
    char* p = (char*)d_ws;
    auto alloc = [&](size_t bytes) -> void* {
        void* r = (void*)p;
        p += (bytes + 255) & ~(size_t)255;
        return r;
    };
    float* deg   = (float*)alloc((size_t)N * 4);        // becomes dis in-place
    int*   hist  = (int*)  alloc((size_t)N * 4);
    int*   rs    = (int*)  alloc((size_t)(N + 1) * 4);
    int*   cursor= (int*)  alloc((size_t)N * 4);
    int*   perm  = (int*)  alloc((size_t)E * 4);
    float* norm  = (float*)alloc((size_t)E * 4);
    float* xw1   = (float*)alloc((size_t)N * 128 * 4);
    float* h1    = (float*)alloc((size_t)N * 128 * 4);
    float* xw2   = (float*)alloc((size_t)N * 64 * 4);
    float* h2    = (float*)alloc((size_t)N * 64 * 4);
    float* g     = (float*)alloc(64 * 64 * 4);
    int*   gcnt  = (int*)  alloc(64 * 4);

    // ---- zero accumulators (ws is poisoned 0xAA before every launch)
    hipMemsetAsync(deg,  0, (size_t)N * 4, stream);
    hipMemsetAsync(hist, 0, (size_t)N * 4, stream);
    hipMemsetAsync(g,    0, 64 * 64 * 4,   stream);
    hipMemsetAsync(gcnt, 0, 64 * 4,        stream);

    // ---- graph preprocessing (shared by both layers)
    k_deg_hist<<<(E + 255) / 256, 256, 0, stream>>>(col, ew, deg, hist, E);
    k_dis<<<(N + 255) / 256, 256, 0, stream>>>(deg, N);
    k_scan<<<1, 1024, 0, stream>>>(hist, rs, cursor, N);
    k_scatter<<<(E + 255) / 256, 256, 0, stream>>>(row, col, ew, deg, cursor, perm, norm, E);

    // ---- layer 1  (gemm: 64 rows/block)
    k_gemm<128><<<(N + 63) / 64, 256, 0, stream>>>(x, W1, xw1, N);
    k_agg<128><<<(N + 7) / 8, 256, 0, stream>>>(xw1, deg, norm, row, rs, perm, b1, h1, N);

    // ---- layer 2  (gemm: 128 rows/block)
    k_gemm<64><<<(N + 127) / 128, 256, 0, stream>>>(h1, W2, xw2, N);
    k_agg<64><<<(N + 15) / 16, 256, 0, stream>>>(xw2, deg, norm, row, rs, perm, b2, h2, N);

    // ---- pool + fc
    k_pool<<<(N + POOL_NODES - 1) / POOL_NODES, 256, 0, stream>>>(h2, batch, g, gcnt, N);
    dim3 fcg((FLAT + 255) / 256, NG);
    k_fc<<<fcg, 256, 0, stream>>>(g, gcnt, Wfc, bfc, out);
}

// Round 4
// 391.715 us; speedup vs baseline: 2.0868x; 1.1892x over previous
//
#include <hip/hip_runtime.h>
#include <hip/hip_bf16.h>

#define NG 64          // number of graphs
#define FLAT 2904      // FC output width
#define K128 128       // inner dim for both GEMMs
#define SC_CHUNK 1024  // scan elements per block

// ---------------------------------------------------------------- utilities
__device__ __forceinline__ float4 ld4(const float* p) { return *(const float4*)p; }
__device__ __forceinline__ void st4(float* p, float4 v) { *(float4*)p = v; }

// ------------------------------------------------- degree + in-degree hist
__global__ void k_deg_hist(const int* __restrict__ col, const float* __restrict__ ew,
                           float* __restrict__ deg, int* __restrict__ hist, int E) {
    int e = blockIdx.x * blockDim.x + threadIdx.x;
    if (e < E) {
        int c = col[e];
        atomicAdd(&deg[c], ew[e]);
        atomicAdd(&hist[c], 1);
    }
}

// deg -> dis = rsqrt(deg + 1)   (self-loop weight 1)
__global__ void k_dis(float* __restrict__ deg, int N) {
    int v = blockIdx.x * blockDim.x + threadIdx.x;
    if (v < N) deg[v] = rsqrtf(deg[v] + 1.0f);
}

// ------------------------------------------------- multi-block scan (3 kernels)
// Replaces the single-block k_scan (92us: 1 CU, per-lane-contiguous access =
// uncoalesced + latency-chained). Each is launch-overhead bound (~4us).

// (1) per-chunk sums: 256 thr x 4 int4-coalesced elements
__global__ __launch_bounds__(256) void k_scan_bsum(const int* __restrict__ hist,
                                                   int* __restrict__ bsum, int N) {
    __shared__ int red[256];
    int tid = threadIdx.x;
    int base = blockIdx.x * SC_CHUNK + tid * 4;
    int s = 0;
    if (base + 4 <= N) {
        int4 v = *(const int4*)(hist + base);
        s = v.x + v.y + v.z + v.w;
    } else {
        for (int i = base; i < N; i++) s += hist[i];
    }
    red[tid] = s;
    __syncthreads();
    for (int off = 128; off > 0; off >>= 1) {
        if (tid < off) red[tid] += red[tid + off];
        __syncthreads();
    }
    if (tid == 0) bsum[blockIdx.x] = red[0];
}

// (2) scan chunk sums (nb <= 256) -> exclusive offsets; total -> rs[N]
__global__ __launch_bounds__(256) void k_scan_boffs(const int* __restrict__ bsum,
                                                    int* __restrict__ boffs,
                                                    int* __restrict__ rsN, int nb) {
    __shared__ int part[256];
    int tid = threadIdx.x;
    part[tid] = (tid < nb) ? bsum[tid] : 0;
    __syncthreads();
    for (int off = 1; off < 256; off <<= 1) {
        int v = (tid >= off) ? part[tid - off] : 0;
        __syncthreads();
        part[tid] += v;
        __syncthreads();
    }
    if (tid < nb) boffs[tid] = (tid > 0) ? part[tid - 1] : 0;
    if (tid == 255) *rsN = part[255];
}

// (3) rescan chunk, add block offset, write rs + cursor (int4 coalesced)
__global__ __launch_bounds__(256) void k_scan_apply(const int* __restrict__ hist,
                                                    const int* __restrict__ boffs,
                                                    int* __restrict__ rs,
                                                    int* __restrict__ cursor, int N) {
    __shared__ int part[256];
    int tid = threadIdx.x;
    int base = blockIdx.x * SC_CHUNK + tid * 4;
    int4 v = make_int4(0, 0, 0, 0);
    if (base + 4 <= N) v = *(const int4*)(hist + base);
    else for (int i = base; i < N; i++) (&v.x)[i - base] = hist[i];
    int s = v.x + v.y + v.z + v.w;
    part[tid] = s;
    __syncthreads();
    for (int off = 1; off < 256; off <<= 1) {
        int t = (tid >= off) ? part[tid - off] : 0;
        __syncthreads();
        part[tid] += t;
        __syncthreads();
    }
    int run = boffs[blockIdx.x] + part[tid] - s;   // exclusive prefix of this thread
    int4 o;
    o.x = run;
    o.y = run + v.x;
    o.z = o.y + v.y;
    o.w = o.z + v.z;
    if (base + 4 <= N) {
        *(int4*)(rs + base) = o;
        *(int4*)(cursor + base) = o;
    } else {
        int vals[4] = {o.x, o.y, o.z, o.w};
        for (int i = base; i < N; i++) { rs[i] = vals[i - base]; cursor[i] = vals[i - base]; }
    }
}

// ------------------------------------------------- scatter edge ids + norm
__global__ void k_scatter(const int* __restrict__ row, const int* __restrict__ col,
                          const float* __restrict__ ew, const float* __restrict__ dis,
                          int* __restrict__ cursor, int* __restrict__ perm,
                          float* __restrict__ norm, int E) {
    int e = blockIdx.x * blockDim.x + threadIdx.x;
    if (e < E) {
        int c = col[e], r = row[e];
        norm[e] = dis[r] * ew[e] * dis[c];
        int pos = atomicAdd(&cursor[c], 1);
        perm[pos] = e;
    }
}

// ------------------------------------------------- fp32 register-tiled GEMM
template <int NCOL>
__global__ __launch_bounds__(256) void k_gemm(const float* __restrict__ A,
                                              const float* __restrict__ W,
                                              float* __restrict__ out, int M) {
    constexpr int JG   = NCOL / 4;    // col groups
    constexpr int RG   = 256 / JG;    // row groups
    constexpr int RPT  = 8;           // rows per thread
    constexpr int ROWS = RG * RPT;    // rows per block
    constexpr int KC   = 32;          // k chunk
    constexpr int AS   = KC + 4;      // A LDS stride

    __shared__ float As[ROWS * AS];
    __shared__ float Ws[KC * NCOL];

    int tid = threadIdx.x;
    int tx  = tid % JG;
    int ty  = tid / JG;
    int row0 = blockIdx.x * ROWS;

    float4 acc[RPT];
#pragma unroll
    for (int i = 0; i < RPT; i++) acc[i] = make_float4(0.f, 0.f, 0.f, 0.f);

    for (int kc = 0; kc < K128; kc += KC) {
#pragma unroll
        for (int q = 0; q < ROWS * 8 / 256; q++) {
            int idx = tid + 256 * q;
            int r   = idx >> 3;
            int f4  = (idx & 7) * 4;
            int gr  = row0 + r; if (gr >= M) gr = M - 1;
            float4 v = ld4(A + (size_t)gr * K128 + kc + f4);
            st4(&As[r * AS + f4], v);
        }
#pragma unroll
        for (int q = 0; q < KC * NCOL / 4 / 256; q++) {
            int idx = (tid + 256 * q) * 4;
            st4(&Ws[idx], ld4(W + (size_t)kc * NCOL + idx));
        }
        __syncthreads();

#pragma unroll
        for (int k4 = 0; k4 < KC; k4 += 4) {
            float4 w0 = ld4(&Ws[(k4 + 0) * NCOL + tx * 4]);
            float4 w1 = ld4(&Ws[(k4 + 1) * NCOL + tx * 4]);
            float4 w2 = ld4(&Ws[(k4 + 2) * NCOL + tx * 4]);
            float4 w3 = ld4(&Ws[(k4 + 3) * NCOL + tx * 4]);
#pragma unroll
            for (int i = 0; i < RPT; i++) {
                float4 a = ld4(&As[(ty + RG * i) * AS + k4]);
                acc[i].x += a.x * w0.x; acc[i].y += a.x * w0.y;
                acc[i].z += a.x * w0.z; acc[i].w += a.x * w0.w;
                acc[i].x += a.y * w1.x; acc[i].y += a.y * w1.y;
                acc[i].z += a.y * w1.z; acc[i].w += a.y * w1.w;
                acc[i].x += a.z * w2.x; acc[i].y += a.z * w2.y;
                acc[i].z += a.z * w2.z; acc[i].w += a.z * w2.w;
                acc[i].x += a.w * w3.x; acc[i].y += a.w * w3.y;
                acc[i].z += a.w * w3.z; acc[i].w += a.w * w3.w;
            }
        }
        __syncthreads();
    }

#pragma unroll
    for (int i = 0; i < RPT; i++) {
        int r = row0 + ty + RG * i;
        if (r < M) st4(out + (size_t)r * NCOL + tx * 4, acc[i]);
    }
}

// ------------------------------------------------- CSR gather aggregation + self + bias + relu
template <int F>
__global__ __launch_bounds__(256) void k_agg(const float* __restrict__ xw,
                                             const float* __restrict__ dis,
                                             const float* __restrict__ norm,
                                             const int* __restrict__ row,
                                             const int* __restrict__ rs,
                                             const int* __restrict__ perm,
                                             const float* __restrict__ bias,
                                             float* __restrict__ out, int N) {
    constexpr int TPN = F / 4;
    constexpr int NPB = 256 / TPN;
    int node = blockIdx.x * NPB + threadIdx.x / TPN;
    int j4   = (threadIdx.x % TPN) * 4;
    if (node >= N) return;
    float dv = dis[node];
    float sw = dv * dv;
    float4 self = ld4(xw + (size_t)node * F + j4);
    float4 bv   = ld4(bias + j4);
    float4 acc;
    acc.x = self.x * sw + bv.x;
    acc.y = self.y * sw + bv.y;
    acc.z = self.z * sw + bv.z;
    acc.w = self.w * sw + bv.w;
    int s = rs[node], e = rs[node + 1];
    for (int j = s; j < e; j++) {
        int ed   = perm[j];
        float nm = norm[ed];
        int r    = row[ed];
        float4 v = ld4(xw + (size_t)r * F + j4);
        acc.x += nm * v.x; acc.y += nm * v.y; acc.z += nm * v.z; acc.w += nm * v.w;
    }
    acc.x = fmaxf(acc.x, 0.f); acc.y = fmaxf(acc.y, 0.f);
    acc.z = fmaxf(acc.z, 0.f); acc.w = fmaxf(acc.w, 0.f);
    st4(out + (size_t)node * F + j4, acc);
}

// ------------------------------------------------- mean-pool accumulate (sorted batch)
#define POOL_NODES 256
__global__ __launch_bounds__(256) void k_pool(const float* __restrict__ h,
                                              const int* __restrict__ batch,
                                              float* __restrict__ g, int* __restrict__ gcnt,
                                              int N) {
    int base  = blockIdx.x * POOL_NODES;
    int f     = threadIdx.x & 63;
    int slice = threadIdx.x >> 6;
    int lim   = base + POOL_NODES; if (lim > N) lim = N;
    float acc = 0.f;
    int cur = -1, cnt = 0;
    for (int i = base + slice; i < lim; i += 4) {
        int b = batch[i];
        if (b != cur) {
            if (cur >= 0) {
                atomicAdd(&g[cur * 64 + f], acc);
                if (f == 0) atomicAdd(&gcnt[cur], cnt);
            }
            cur = b; acc = 0.f; cnt = 0;
        }
        acc += h[(size_t)i * 64 + f];
        cnt++;
    }
    if (cur >= 0) {
        atomicAdd(&g[cur * 64 + f], acc);
        if (f == 0) atomicAdd(&gcnt[cur], cnt);
    }
}

// ------------------------------------------------- FC: out[NG,FLAT] = (g/cnt) @ Wfc + bfc
__global__ __launch_bounds__(256) void k_fc(const float* __restrict__ g,
                                            const int* __restrict__ gcnt,
                                            const float* __restrict__ Wfc,
                                            const float* __restrict__ bfc,
                                            float* __restrict__ out) {
    __shared__ float gs[64];
    int i = blockIdx.y;
    int j = blockIdx.x * blockDim.x + threadIdx.x;
    if (threadIdx.x < 64) {
        float c = (float)gcnt[i];
        gs[threadIdx.x] = g[i * 64 + threadIdx.x] / fmaxf(c, 1.0f);
    }
    __syncthreads();
    if (j >= FLAT) return;
    float acc = bfc[j];
#pragma unroll 8
    for (int k = 0; k < 64; k++) acc += gs[k] * Wfc[k * FLAT + j];
    out[(size_t)i * FLAT + j] = acc;
}

// ================================================================ launcher
extern "C" void kernel_launch(void* const* d_in, const int* in_sizes, int n_in,
                              void* d_out, int out_size, void* d_ws, size_t ws_size,
                              hipStream_t stream) {
    const float* x    = (const float*)d_in[0];
    const int*   ei   = (const int*)d_in[1];
    const float* ew   = (const float*)d_in[2];
    const int*   batch= (const int*)d_in[3];
    const float* W1   = (const float*)d_in[4];
    const float* b1   = (const float*)d_in[5];
    const float* W2   = (const float*)d_in[6];
    const float* b2   = (const float*)d_in[7];
    const float* Wfc  = (const float*)d_in[8];
    const float* bfc  = (const float*)d_in[9];
    float* out = (float*)d_out;

    const int N = in_sizes[0] / K128;   // 40000
    const int E = in_sizes[2];          // 640000
    const int* row = ei;
    const int* col = ei + E;
    const int nb = (N + SC_CHUNK - 1) / SC_CHUNK;   // 40 scan chunks

    // ---- workspace carve (256B aligned)
    char* p = (char*)d_ws;
    auto alloc = [&](size_t bytes) -> void* {
        void* r = (void*)p;
        p += (bytes + 255) & ~(size_t)255;
        return r;
    };
    float* deg   = (float*)alloc((size_t)N * 4);        // becomes dis in-place
    int*   hist  = (int*)  alloc((size_t)N * 4);
    int*   rs    = (int*)  alloc((size_t)(N + 1) * 4);
    int*   cursor= (int*)  alloc((size_t)N * 4);
    int*   perm  = (int*)  alloc((size_t)E * 4);
    float* norm  = (float*)alloc((size_t)E * 4);
    float* xw1   = (float*)alloc((size_t)N * 128 * 4);
    float* h1    = (float*)alloc((size_t)N * 128 * 4);
    float* xw2   = (float*)alloc((size_t)N * 64 * 4);
    float* h2    = (float*)alloc((size_t)N * 64 * 4);
    float* g     = (float*)alloc(64 * 64 * 4);
    int*   gcnt  = (int*)  alloc(64 * 4);
    int*   bsum  = (int*)  alloc(256 * 4);
    int*   boffs = (int*)  alloc(256 * 4);

    // ---- zero accumulators (ws is poisoned 0xAA before every launch)
    hipMemsetAsync(deg,  0, (size_t)N * 4, stream);
    hipMemsetAsync(hist, 0, (size_t)N * 4, stream);
    hipMemsetAsync(g,    0, 64 * 64 * 4,   stream);
    hipMemsetAsync(gcnt, 0, 64 * 4,        stream);

    // ---- graph preprocessing (shared by both layers)
    k_deg_hist<<<(E + 255) / 256, 256, 0, stream>>>(col, ew, deg, hist, E);
    k_dis<<<(N + 255) / 256, 256, 0, stream>>>(deg, N);
    k_scan_bsum<<<nb, 256, 0, stream>>>(hist, bsum, N);
    k_scan_boffs<<<1, 256, 0, stream>>>(bsum, boffs, rs + N, nb);
    k_scan_apply<<<nb, 256, 0, stream>>>(hist, boffs, rs, cursor, N);
    k_scatter<<<(E + 255) / 256, 256, 0, stream>>>(row, col, ew, deg, cursor, perm, norm, E);

    // ---- layer 1  (gemm: 64 rows/block)
    k_gemm<128><<<(N + 63) / 64, 256, 0, stream>>>(x, W1, xw1, N);
    k_agg<128><<<(N + 7) / 8, 256, 0, stream>>>(xw1, deg, norm, row, rs, perm, b1, h1, N);

    // ---- layer 2  (gemm: 128 rows/block)
    k_gemm<64><<<(N + 127) / 128, 256, 0, stream>>>(h1, W2, xw2, N);
    k_agg<64><<<(N + 15) / 16, 256, 0, stream>>>(xw2, deg, norm, row, rs, perm, b2, h2, N);

    // ---- pool + fc
    k_pool<<<(N + POOL_NODES - 1) / POOL_NODES, 256, 0, stream>>>(h2, batch, g, gcnt, N);
    dim3 fcg((FLAT + 255) / 256, NG);
    k_fc<<<fcg, 256, 0, stream>>>(g, gcnt, Wfc, bfc, out);
}

// Round 5
// 375.021 us; speedup vs baseline: 2.1797x; 1.0445x over previous
//
#include <hip/hip_runtime.h>
#include <hip/hip_bf16.h>
#include <hip/hip_fp16.h>
#include <type_traits>

#define NG 64          // number of graphs
#define FLAT 2904      // FC output width
#define K128 128       // inner dim for both GEMMs
#define SC_CHUNK 1024  // scan elements per block

typedef _Float16 h4 __attribute__((ext_vector_type(4)));  // 8B, align 8

// ---------------------------------------------------------------- utilities
__device__ __forceinline__ float4 ld4(const float* p) { return *(const float4*)p; }
__device__ __forceinline__ void st4(float* p, float4 v) { *(float4*)p = v; }
__device__ __forceinline__ float4 ldh4(const _Float16* p) {
    h4 h = *(const h4*)p;
    return make_float4((float)h.x, (float)h.y, (float)h.z, (float)h.w);
}
__device__ __forceinline__ void sth4(_Float16* p, float4 v) {
    h4 h; h.x = (_Float16)v.x; h.y = (_Float16)v.y; h.z = (_Float16)v.z; h.w = (_Float16)v.w;
    *(h4*)p = h;
}

// ------------------------------------------------- degree + in-degree hist
__global__ void k_deg_hist(const int* __restrict__ col, const float* __restrict__ ew,
                           float* __restrict__ deg, int* __restrict__ hist, int E) {
    int e = blockIdx.x * blockDim.x + threadIdx.x;
    if (e < E) {
        int c = col[e];
        atomicAdd(&deg[c], ew[e]);
        atomicAdd(&hist[c], 1);
    }
}

// deg -> dis = rsqrt(deg + 1)   (self-loop weight 1)
__global__ void k_dis(float* __restrict__ deg, int N) {
    int v = blockIdx.x * blockDim.x + threadIdx.x;
    if (v < N) deg[v] = rsqrtf(deg[v] + 1.0f);
}

// ------------------------------------------------- multi-block scan (3 kernels)
__global__ __launch_bounds__(256) void k_scan_bsum(const int* __restrict__ hist,
                                                   int* __restrict__ bsum, int N) {
    __shared__ int red[256];
    int tid = threadIdx.x;
    int base = blockIdx.x * SC_CHUNK + tid * 4;
    int s = 0;
    if (base + 4 <= N) {
        int4 v = *(const int4*)(hist + base);
        s = v.x + v.y + v.z + v.w;
    } else {
        for (int i = base; i < N; i++) s += hist[i];
    }
    red[tid] = s;
    __syncthreads();
    for (int off = 128; off > 0; off >>= 1) {
        if (tid < off) red[tid] += red[tid + off];
        __syncthreads();
    }
    if (tid == 0) bsum[blockIdx.x] = red[0];
}

__global__ __launch_bounds__(256) void k_scan_boffs(const int* __restrict__ bsum,
                                                    int* __restrict__ boffs,
                                                    int* __restrict__ rsN, int nb) {
    __shared__ int part[256];
    int tid = threadIdx.x;
    part[tid] = (tid < nb) ? bsum[tid] : 0;
    __syncthreads();
    for (int off = 1; off < 256; off <<= 1) {
        int v = (tid >= off) ? part[tid - off] : 0;
        __syncthreads();
        part[tid] += v;
        __syncthreads();
    }
    if (tid < nb) boffs[tid] = (tid > 0) ? part[tid - 1] : 0;
    if (tid == 255) *rsN = part[255];
}

__global__ __launch_bounds__(256) void k_scan_apply(const int* __restrict__ hist,
                                                    const int* __restrict__ boffs,
                                                    int* __restrict__ rs,
                                                    int* __restrict__ cursor, int N) {
    __shared__ int part[256];
    int tid = threadIdx.x;
    int base = blockIdx.x * SC_CHUNK + tid * 4;
    int4 v = make_int4(0, 0, 0, 0);
    if (base + 4 <= N) v = *(const int4*)(hist + base);
    else for (int i = base; i < N; i++) (&v.x)[i - base] = hist[i];
    int s = v.x + v.y + v.z + v.w;
    part[tid] = s;
    __syncthreads();
    for (int off = 1; off < 256; off <<= 1) {
        int t = (tid >= off) ? part[tid - off] : 0;
        __syncthreads();
        part[tid] += t;
        __syncthreads();
    }
    int run = boffs[blockIdx.x] + part[tid] - s;
    int4 o;
    o.x = run;
    o.y = run + v.x;
    o.z = o.y + v.y;
    o.w = o.z + v.z;
    if (base + 4 <= N) {
        *(int4*)(rs + base) = o;
        *(int4*)(cursor + base) = o;
    } else {
        int vals[4] = {o.x, o.y, o.z, o.w};
        for (int i = base; i < N; i++) { rs[i] = vals[i - base]; cursor[i] = vals[i - base]; }
    }
}

// ------------------------------------------------- scatter edge ids + norm
__global__ void k_scatter(const int* __restrict__ row, const int* __restrict__ col,
                          const float* __restrict__ ew, const float* __restrict__ dis,
                          int* __restrict__ cursor, int* __restrict__ perm,
                          float* __restrict__ norm, int E) {
    int e = blockIdx.x * blockDim.x + threadIdx.x;
    if (e < E) {
        int c = col[e], r = row[e];
        norm[e] = dis[r] * ew[e] * dis[c];
        int pos = atomicAdd(&cursor[c], 1);
        perm[pos] = e;
    }
}

// ------------------------------------------------- fp32 register-tiled GEMM, fp16 out
// A: float (layer1 input x) or _Float16 (layer2 input h1); out: fp16.
template <int NCOL, typename AT>
__global__ __launch_bounds__(256) void k_gemm(const AT* __restrict__ A,
                                              const float* __restrict__ W,
                                              _Float16* __restrict__ out, int M) {
    constexpr int JG   = NCOL / 4;
    constexpr int RG   = 256 / JG;
    constexpr int RPT  = 8;
    constexpr int ROWS = RG * RPT;
    constexpr int KC   = 32;
    constexpr int AS   = KC + 4;

    __shared__ float As[ROWS * AS];
    __shared__ float Ws[KC * NCOL];

    int tid = threadIdx.x;
    int tx  = tid % JG;
    int ty  = tid / JG;
    int row0 = blockIdx.x * ROWS;

    float4 acc[RPT];
#pragma unroll
    for (int i = 0; i < RPT; i++) acc[i] = make_float4(0.f, 0.f, 0.f, 0.f);

    for (int kc = 0; kc < K128; kc += KC) {
#pragma unroll
        for (int q = 0; q < ROWS * 8 / 256; q++) {
            int idx = tid + 256 * q;
            int r   = idx >> 3;
            int f4  = (idx & 7) * 4;
            int gr  = row0 + r; if (gr >= M) gr = M - 1;
            float4 v;
            if constexpr (std::is_same_v<AT, float>) v = ld4(A + (size_t)gr * K128 + kc + f4);
            else                                     v = ldh4(A + (size_t)gr * K128 + kc + f4);
            st4(&As[r * AS + f4], v);
        }
#pragma unroll
        for (int q = 0; q < KC * NCOL / 4 / 256; q++) {
            int idx = (tid + 256 * q) * 4;
            st4(&Ws[idx], ld4(W + (size_t)kc * NCOL + idx));
        }
        __syncthreads();

#pragma unroll
        for (int k4 = 0; k4 < KC; k4 += 4) {
            float4 w0 = ld4(&Ws[(k4 + 0) * NCOL + tx * 4]);
            float4 w1 = ld4(&Ws[(k4 + 1) * NCOL + tx * 4]);
            float4 w2 = ld4(&Ws[(k4 + 2) * NCOL + tx * 4]);
            float4 w3 = ld4(&Ws[(k4 + 3) * NCOL + tx * 4]);
#pragma unroll
            for (int i = 0; i < RPT; i++) {
                float4 a = ld4(&As[(ty + RG * i) * AS + k4]);
                acc[i].x += a.x * w0.x; acc[i].y += a.x * w0.y;
                acc[i].z += a.x * w0.z; acc[i].w += a.x * w0.w;
                acc[i].x += a.y * w1.x; acc[i].y += a.y * w1.y;
                acc[i].z += a.y * w1.z; acc[i].w += a.y * w1.w;
                acc[i].x += a.z * w2.x; acc[i].y += a.z * w2.y;
                acc[i].z += a.z * w2.z; acc[i].w += a.z * w2.w;
                acc[i].x += a.w * w3.x; acc[i].y += a.w * w3.y;
                acc[i].z += a.w * w3.z; acc[i].w += a.w * w3.w;
            }
        }
        __syncthreads();
    }

#pragma unroll
    for (int i = 0; i < RPT; i++) {
        int r = row0 + ty + RG * i;
        if (r < M) sth4(out + (size_t)r * NCOL + tx * 4, acc[i]);
    }
}

// ------------------------------------------------- CSR gather agg (fp16 in/out, fp32 acc)
template <int F>
__global__ __launch_bounds__(256) void k_agg(const _Float16* __restrict__ xw,
                                             const float* __restrict__ dis,
                                             const float* __restrict__ norm,
                                             const int* __restrict__ row,
                                             const int* __restrict__ rs,
                                             const int* __restrict__ perm,
                                             const float* __restrict__ bias,
                                             _Float16* __restrict__ out, int N) {
    constexpr int TPN = F / 4;
    constexpr int NPB = 256 / TPN;
    int node = blockIdx.x * NPB + threadIdx.x / TPN;
    int j4   = (threadIdx.x % TPN) * 4;
    if (node >= N) return;
    float dv = dis[node];
    float sw = dv * dv;
    float4 self = ldh4(xw + (size_t)node * F + j4);
    float4 bv   = ld4(bias + j4);
    float4 acc;
    acc.x = self.x * sw + bv.x;
    acc.y = self.y * sw + bv.y;
    acc.z = self.z * sw + bv.z;
    acc.w = self.w * sw + bv.w;
    int s = rs[node], e = rs[node + 1];
    for (int j = s; j < e; j++) {
        int ed   = perm[j];
        float nm = norm[ed];
        int r    = row[ed];
        float4 v = ldh4(xw + (size_t)r * F + j4);
        acc.x += nm * v.x; acc.y += nm * v.y; acc.z += nm * v.z; acc.w += nm * v.w;
    }
    acc.x = fmaxf(acc.x, 0.f); acc.y = fmaxf(acc.y, 0.f);
    acc.z = fmaxf(acc.z, 0.f); acc.w = fmaxf(acc.w, 0.f);
    sth4(out + (size_t)node * F + j4, acc);
}

// ------------------------------------------------- mean-pool accumulate (sorted batch)
#define POOL_NODES 256
__global__ __launch_bounds__(256) void k_pool(const _Float16* __restrict__ h,
                                              const int* __restrict__ batch,
                                              float* __restrict__ g, int* __restrict__ gcnt,
                                              int N) {
    int base  = blockIdx.x * POOL_NODES;
    int f     = threadIdx.x & 63;
    int slice = threadIdx.x >> 6;
    int lim   = base + POOL_NODES; if (lim > N) lim = N;
    float acc = 0.f;
    int cur = -1, cnt = 0;
    for (int i = base + slice; i < lim; i += 4) {
        int b = batch[i];
        if (b != cur) {
            if (cur >= 0) {
                atomicAdd(&g[cur * 64 + f], acc);
                if (f == 0) atomicAdd(&gcnt[cur], cnt);
            }
            cur = b; acc = 0.f; cnt = 0;
        }
        acc += (float)h[(size_t)i * 64 + f];
        cnt++;
    }
    if (cur >= 0) {
        atomicAdd(&g[cur * 64 + f], acc);
        if (f == 0) atomicAdd(&gcnt[cur], cnt);
    }
}

// ------------------------------------------------- FC: out[NG,FLAT] = (g/cnt) @ Wfc + bfc
__global__ __launch_bounds__(256) void k_fc(const float* __restrict__ g,
                                            const int* __restrict__ gcnt,
                                            const float* __restrict__ Wfc,
                                            const float* __restrict__ bfc,
                                            float* __restrict__ out) {
    __shared__ float gs[64];
    int i = blockIdx.y;
    int j = blockIdx.x * blockDim.x + threadIdx.x;
    if (threadIdx.x < 64) {
        float c = (float)gcnt[i];
        gs[threadIdx.x] = g[i * 64 + threadIdx.x] / fmaxf(c, 1.0f);
    }
    __syncthreads();
    if (j >= FLAT) return;
    float acc = bfc[j];
#pragma unroll 8
    for (int k = 0; k < 64; k++) acc += gs[k] * Wfc[k * FLAT + j];
    out[(size_t)i * FLAT + j] = acc;
}

// ================================================================ launcher
extern "C" void kernel_launch(void* const* d_in, const int* in_sizes, int n_in,
                              void* d_out, int out_size, void* d_ws, size_t ws_size,
                              hipStream_t stream) {
    const float* x    = (const float*)d_in[0];
    const int*   ei   = (const int*)d_in[1];
    const float* ew   = (const float*)d_in[2];
    const int*   batch= (const int*)d_in[3];
    const float* W1   = (const float*)d_in[4];
    const float* b1   = (const float*)d_in[5];
    const float* W2   = (const float*)d_in[6];
    const float* b2   = (const float*)d_in[7];
    const float* Wfc  = (const float*)d_in[8];
    const float* bfc  = (const float*)d_in[9];
    float* out = (float*)d_out;

    const int N = in_sizes[0] / K128;   // 40000
    const int E = in_sizes[2];          // 640000
    const int* row = ei;
    const int* col = ei + E;
    const int nb = (N + SC_CHUNK - 1) / SC_CHUNK;

    // ---- workspace carve (256B aligned)
    char* p = (char*)d_ws;
    auto alloc = [&](size_t bytes) -> void* {
        void* r = (void*)p;
        p += (bytes + 255) & ~(size_t)255;
        return r;
    };
    float*     deg   = (float*)    alloc((size_t)N * 4);   // becomes dis in-place
    int*       hist  = (int*)      alloc((size_t)N * 4);
    int*       rs    = (int*)      alloc((size_t)(N + 1) * 4);
    int*       cursor= (int*)      alloc((size_t)N * 4);
    int*       perm  = (int*)      alloc((size_t)E * 4);
    float*     norm  = (float*)    alloc((size_t)E * 4);
    _Float16*  xw1   = (_Float16*) alloc((size_t)N * 128 * 2);
    _Float16*  h1    = (_Float16*) alloc((size_t)N * 128 * 2);
    _Float16*  xw2   = (_Float16*) alloc((size_t)N * 64 * 2);
    _Float16*  h2    = (_Float16*) alloc((size_t)N * 64 * 2);
    float*     g     = (float*)    alloc(64 * 64 * 4);
    int*       gcnt  = (int*)      alloc(64 * 4);
    int*       bsum  = (int*)      alloc(256 * 4);
    int*       boffs = (int*)      alloc(256 * 4);

    // ---- zero accumulators (ws is poisoned 0xAA before every launch)
    hipMemsetAsync(deg,  0, (size_t)N * 4, stream);
    hipMemsetAsync(hist, 0, (size_t)N * 4, stream);
    hipMemsetAsync(g,    0, 64 * 64 * 4,   stream);
    hipMemsetAsync(gcnt, 0, 64 * 4,        stream);

    // ---- graph preprocessing (shared by both layers)
    k_deg_hist<<<(E + 255) / 256, 256, 0, stream>>>(col, ew, deg, hist, E);
    k_dis<<<(N + 255) / 256, 256, 0, stream>>>(deg, N);
    k_scan_bsum<<<nb, 256, 0, stream>>>(hist, bsum, N);
    k_scan_boffs<<<1, 256, 0, stream>>>(bsum, boffs, rs + N, nb);
    k_scan_apply<<<nb, 256, 0, stream>>>(hist, boffs, rs, cursor, N);
    k_scatter<<<(E + 255) / 256, 256, 0, stream>>>(row, col, ew, deg, cursor, perm, norm, E);

    // ---- layer 1
    k_gemm<128, float><<<(N + 63) / 64, 256, 0, stream>>>(x, W1, xw1, N);
    k_agg<128><<<(N + 7) / 8, 256, 0, stream>>>(xw1, deg, norm, row, rs, perm, b1, h1, N);

    // ---- layer 2
    k_gemm<64, _Float16><<<(N + 127) / 128, 256, 0, stream>>>(h1, W2, xw2, N);
    k_agg<64><<<(N + 15) / 16, 256, 0, stream>>>(xw2, deg, norm, row, rs, perm, b2, h2, N);

    // ---- pool + fc
    k_pool<<<(N + POOL_NODES - 1) / POOL_NODES, 256, 0, stream>>>(h2, batch, g, gcnt, N);
    dim3 fcg((FLAT + 255) / 256, NG);
    k_fc<<<fcg, 256, 0, stream>>>(g, gcnt, Wfc, bfc, out);
}

// Round 6
// 308.298 us; speedup vs baseline: 2.6515x; 1.2164x over previous
//
#include <hip/hip_runtime.h>
#include <hip/hip_bf16.h>
#include <hip/hip_fp16.h>
#include <type_traits>

#define NG 64          // number of graphs
#define FLAT 2904      // FC output width
#define K128 128       // inner dim for both GEMMs
#define SC_CHUNK 1024  // scan elements per block

typedef _Float16 h4 __attribute__((ext_vector_type(4)));  // 8B, align 8

// ---------------------------------------------------------------- utilities
__device__ __forceinline__ float4 ld4(const float* p) { return *(const float4*)p; }
__device__ __forceinline__ void st4(float* p, float4 v) { *(float4*)p = v; }
__device__ __forceinline__ float4 ldh4(const _Float16* p) {
    h4 h = *(const h4*)p;
    return make_float4((float)h.x, (float)h.y, (float)h.z, (float)h.w);
}
__device__ __forceinline__ void sth4(_Float16* p, float4 v) {
    h4 h; h.x = (_Float16)v.x; h.y = (_Float16)v.y; h.z = (_Float16)v.z; h.w = (_Float16)v.w;
    *(h4*)p = h;
}

// ------------------------------------------------- degree + in-degree hist
__global__ void k_deg_hist(const int* __restrict__ col, const float* __restrict__ ew,
                           float* __restrict__ deg, int* __restrict__ hist, int E) {
    int e = blockIdx.x * blockDim.x + threadIdx.x;
    if (e < E) {
        int c = col[e];
        atomicAdd(&deg[c], ew[e]);
        atomicAdd(&hist[c], 1);
    }
}

// deg -> dis = rsqrt(deg + 1)   (self-loop weight 1)
__global__ void k_dis(float* __restrict__ deg, int N) {
    int v = blockIdx.x * blockDim.x + threadIdx.x;
    if (v < N) deg[v] = rsqrtf(deg[v] + 1.0f);
}

// ------------------------------------------------- multi-block scan (3 kernels)
__global__ __launch_bounds__(256) void k_scan_bsum(const int* __restrict__ hist,
                                                   int* __restrict__ bsum, int N) {
    __shared__ int red[256];
    int tid = threadIdx.x;
    int base = blockIdx.x * SC_CHUNK + tid * 4;
    int s = 0;
    if (base + 4 <= N) {
        int4 v = *(const int4*)(hist + base);
        s = v.x + v.y + v.z + v.w;
    } else {
        for (int i = base; i < N; i++) s += hist[i];
    }
    red[tid] = s;
    __syncthreads();
    for (int off = 128; off > 0; off >>= 1) {
        if (tid < off) red[tid] += red[tid + off];
        __syncthreads();
    }
    if (tid == 0) bsum[blockIdx.x] = red[0];
}

__global__ __launch_bounds__(256) void k_scan_boffs(const int* __restrict__ bsum,
                                                    int* __restrict__ boffs,
                                                    int* __restrict__ rsN, int nb) {
    __shared__ int part[256];
    int tid = threadIdx.x;
    part[tid] = (tid < nb) ? bsum[tid] : 0;
    __syncthreads();
    for (int off = 1; off < 256; off <<= 1) {
        int v = (tid >= off) ? part[tid - off] : 0;
        __syncthreads();
        part[tid] += v;
        __syncthreads();
    }
    if (tid < nb) boffs[tid] = (tid > 0) ? part[tid - 1] : 0;
    if (tid == 255) *rsN = part[255];
}

__global__ __launch_bounds__(256) void k_scan_apply(const int* __restrict__ hist,
                                                    const int* __restrict__ boffs,
                                                    int* __restrict__ rs,
                                                    int* __restrict__ cursor, int N) {
    __shared__ int part[256];
    int tid = threadIdx.x;
    int base = blockIdx.x * SC_CHUNK + tid * 4;
    int4 v = make_int4(0, 0, 0, 0);
    if (base + 4 <= N) v = *(const int4*)(hist + base);
    else for (int i = base; i < N; i++) (&v.x)[i - base] = hist[i];
    int s = v.x + v.y + v.z + v.w;
    part[tid] = s;
    __syncthreads();
    for (int off = 1; off < 256; off <<= 1) {
        int t = (tid >= off) ? part[tid - off] : 0;
        __syncthreads();
        part[tid] += t;
        __syncthreads();
    }
    int run = boffs[blockIdx.x] + part[tid] - s;
    int4 o;
    o.x = run;
    o.y = run + v.x;
    o.z = o.y + v.y;
    o.w = o.z + v.z;
    if (base + 4 <= N) {
        *(int4*)(rs + base) = o;
        *(int4*)(cursor + base) = o;
    } else {
        int vals[4] = {o.x, o.y, o.z, o.w};
        for (int i = base; i < N; i++) { rs[i] = vals[i - base]; cursor[i] = vals[i - base]; }
    }
}

// ------------------------------------------------- scatter: edge-sorted (row,norm) pairs
// edata[pos] = {src_row, bits(norm)} so the agg kernel streams metadata
// sequentially (one fewer random-indirection level in its load chain).
__global__ void k_scatter(const int* __restrict__ row, const int* __restrict__ col,
                          const float* __restrict__ ew, const float* __restrict__ dis,
                          int* __restrict__ cursor, int2* __restrict__ edata, int E) {
    int e = blockIdx.x * blockDim.x + threadIdx.x;
    if (e < E) {
        int c = col[e], r = row[e];
        float nm = dis[r] * ew[e] * dis[c];
        int pos = atomicAdd(&cursor[c], 1);
        edata[pos] = make_int2(r, __float_as_int(nm));
    }
}

// ------------------------------------------------- fp32 register-tiled GEMM, fp16 out
template <int NCOL, typename AT>
__global__ __launch_bounds__(256) void k_gemm(const AT* __restrict__ A,
                                              const float* __restrict__ W,
                                              _Float16* __restrict__ out, int M) {
    constexpr int JG   = NCOL / 4;
    constexpr int RG   = 256 / JG;
    constexpr int RPT  = 8;
    constexpr int ROWS = RG * RPT;
    constexpr int KC   = 32;
    constexpr int AS   = KC + 4;

    __shared__ float As[ROWS * AS];
    __shared__ float Ws[KC * NCOL];

    int tid = threadIdx.x;
    int tx  = tid % JG;
    int ty  = tid / JG;
    int row0 = blockIdx.x * ROWS;

    float4 acc[RPT];
#pragma unroll
    for (int i = 0; i < RPT; i++) acc[i] = make_float4(0.f, 0.f, 0.f, 0.f);

    for (int kc = 0; kc < K128; kc += KC) {
#pragma unroll
        for (int q = 0; q < ROWS * 8 / 256; q++) {
            int idx = tid + 256 * q;
            int r   = idx >> 3;
            int f4  = (idx & 7) * 4;
            int gr  = row0 + r; if (gr >= M) gr = M - 1;
            float4 v;
            if constexpr (std::is_same_v<AT, float>) v = ld4(A + (size_t)gr * K128 + kc + f4);
            else                                     v = ldh4(A + (size_t)gr * K128 + kc + f4);
            st4(&As[r * AS + f4], v);
        }
#pragma unroll
        for (int q = 0; q < KC * NCOL / 4 / 256; q++) {
            int idx = (tid + 256 * q) * 4;
            st4(&Ws[idx], ld4(W + (size_t)kc * NCOL + idx));
        }
        __syncthreads();

#pragma unroll
        for (int k4 = 0; k4 < KC; k4 += 4) {
            float4 w0 = ld4(&Ws[(k4 + 0) * NCOL + tx * 4]);
            float4 w1 = ld4(&Ws[(k4 + 1) * NCOL + tx * 4]);
            float4 w2 = ld4(&Ws[(k4 + 2) * NCOL + tx * 4]);
            float4 w3 = ld4(&Ws[(k4 + 3) * NCOL + tx * 4]);
#pragma unroll
            for (int i = 0; i < RPT; i++) {
                float4 a = ld4(&As[(ty + RG * i) * AS + k4]);
                acc[i].x += a.x * w0.x; acc[i].y += a.x * w0.y;
                acc[i].z += a.x * w0.z; acc[i].w += a.x * w0.w;
                acc[i].x += a.y * w1.x; acc[i].y += a.y * w1.y;
                acc[i].z += a.y * w1.z; acc[i].w += a.y * w1.w;
                acc[i].x += a.z * w2.x; acc[i].y += a.z * w2.y;
                acc[i].z += a.z * w2.z; acc[i].w += a.z * w2.w;
                acc[i].x += a.w * w3.x; acc[i].y += a.w * w3.y;
                acc[i].z += a.w * w3.z; acc[i].w += a.w * w3.w;
            }
        }
        __syncthreads();
    }

#pragma unroll
    for (int i = 0; i < RPT; i++) {
        int r = row0 + ty + RG * i;
        if (r < M) sth4(out + (size_t)r * NCOL + tx * 4, acc[i]);
    }
}

// ------------------------------------------------- CSR gather agg, 4-way ILP
// fp16 in/out, fp32 acc. Edge metadata streamed from edata (sequential);
// only the xw row gather is random. 4 independent accumulators keep 4
// gather loads in flight (was: 1 serial chain -> latency-bound, VALU 15%).
template <int F>
__global__ __launch_bounds__(256) void k_agg(const _Float16* __restrict__ xw,
                                             const float* __restrict__ dis,
                                             const int2* __restrict__ edata,
                                             const int* __restrict__ rs,
                                             const float* __restrict__ bias,
                                             _Float16* __restrict__ out, int N) {
    constexpr int TPN = F / 4;
    constexpr int NPB = 256 / TPN;
    int node = blockIdx.x * NPB + threadIdx.x / TPN;
    int j4   = (threadIdx.x % TPN) * 4;
    if (node >= N) return;
    float dv = dis[node];
    float sw = dv * dv;
    float4 self = ldh4(xw + (size_t)node * F + j4);
    float4 bv   = ld4(bias + j4);
    float4 a0, a1, a2, a3;
    a0.x = self.x * sw + bv.x;
    a0.y = self.y * sw + bv.y;
    a0.z = self.z * sw + bv.z;
    a0.w = self.w * sw + bv.w;
    a1 = make_float4(0.f, 0.f, 0.f, 0.f);
    a2 = a1; a3 = a1;
    int s = rs[node], e = rs[node + 1];
    int j = s;
    for (; j + 4 <= e; j += 4) {
        int2 q0 = edata[j + 0];
        int2 q1 = edata[j + 1];
        int2 q2 = edata[j + 2];
        int2 q3 = edata[j + 3];
        float4 v0 = ldh4(xw + (size_t)q0.x * F + j4);
        float4 v1 = ldh4(xw + (size_t)q1.x * F + j4);
        float4 v2 = ldh4(xw + (size_t)q2.x * F + j4);
        float4 v3 = ldh4(xw + (size_t)q3.x * F + j4);
        float n0 = __int_as_float(q0.y), n1 = __int_as_float(q1.y);
        float n2 = __int_as_float(q2.y), n3 = __int_as_float(q3.y);
        a0.x += n0 * v0.x; a0.y += n0 * v0.y; a0.z += n0 * v0.z; a0.w += n0 * v0.w;
        a1.x += n1 * v1.x; a1.y += n1 * v1.y; a1.z += n1 * v1.z; a1.w += n1 * v1.w;
        a2.x += n2 * v2.x; a2.y += n2 * v2.y; a2.z += n2 * v2.z; a2.w += n2 * v2.w;
        a3.x += n3 * v3.x; a3.y += n3 * v3.y; a3.z += n3 * v3.z; a3.w += n3 * v3.w;
    }
    for (; j < e; j++) {
        int2 q = edata[j];
        float nm = __int_as_float(q.y);
        float4 v = ldh4(xw + (size_t)q.x * F + j4);
        a0.x += nm * v.x; a0.y += nm * v.y; a0.z += nm * v.z; a0.w += nm * v.w;
    }
    float4 acc;
    acc.x = (a0.x + a1.x) + (a2.x + a3.x);
    acc.y = (a0.y + a1.y) + (a2.y + a3.y);
    acc.z = (a0.z + a1.z) + (a2.z + a3.z);
    acc.w = (a0.w + a1.w) + (a2.w + a3.w);
    acc.x = fmaxf(acc.x, 0.f); acc.y = fmaxf(acc.y, 0.f);
    acc.z = fmaxf(acc.z, 0.f); acc.w = fmaxf(acc.w, 0.f);
    sth4(out + (size_t)node * F + j4, acc);
}

// ------------------------------------------------- mean-pool accumulate (sorted batch)
#define POOL_NODES 256
__global__ __launch_bounds__(256) void k_pool(const _Float16* __restrict__ h,
                                              const int* __restrict__ batch,
                                              float* __restrict__ g, int* __restrict__ gcnt,
                                              int N) {
    int base  = blockIdx.x * POOL_NODES;
    int f     = threadIdx.x & 63;
    int slice = threadIdx.x >> 6;
    int lim   = base + POOL_NODES; if (lim > N) lim = N;
    float acc = 0.f;
    int cur = -1, cnt = 0;
    for (int i = base + slice; i < lim; i += 4) {
        int b = batch[i];
        if (b != cur) {
            if (cur >= 0) {
                atomicAdd(&g[cur * 64 + f], acc);
                if (f == 0) atomicAdd(&gcnt[cur], cnt);
            }
            cur = b; acc = 0.f; cnt = 0;
        }
        acc += (float)h[(size_t)i * 64 + f];
        cnt++;
    }
    if (cur >= 0) {
        atomicAdd(&g[cur * 64 + f], acc);
        if (f == 0) atomicAdd(&gcnt[cur], cnt);
    }
}

// ------------------------------------------------- FC: out[NG,FLAT] = (g/cnt) @ Wfc + bfc
__global__ __launch_bounds__(256) void k_fc(const float* __restrict__ g,
                                            const int* __restrict__ gcnt,
                                            const float* __restrict__ Wfc,
                                            const float* __restrict__ bfc,
                                            float* __restrict__ out) {
    __shared__ float gs[64];
    int i = blockIdx.y;
    int j = blockIdx.x * blockDim.x + threadIdx.x;
    if (threadIdx.x < 64) {
        float c = (float)gcnt[i];
        gs[threadIdx.x] = g[i * 64 + threadIdx.x] / fmaxf(c, 1.0f);
    }
    __syncthreads();
    if (j >= FLAT) return;
    float acc = bfc[j];
#pragma unroll 8
    for (int k = 0; k < 64; k++) acc += gs[k] * Wfc[k * FLAT + j];
    out[(size_t)i * FLAT + j] = acc;
}

// ================================================================ launcher
extern "C" void kernel_launch(void* const* d_in, const int* in_sizes, int n_in,
                              void* d_out, int out_size, void* d_ws, size_t ws_size,
                              hipStream_t stream) {
    const float* x    = (const float*)d_in[0];
    const int*   ei   = (const int*)d_in[1];
    const float* ew   = (const float*)d_in[2];
    const int*   batch= (const int*)d_in[3];
    const float* W1   = (const float*)d_in[4];
    const float* b1   = (const float*)d_in[5];
    const float* W2   = (const float*)d_in[6];
    const float* b2   = (const float*)d_in[7];
    const float* Wfc  = (const float*)d_in[8];
    const float* bfc  = (const float*)d_in[9];
    float* out = (float*)d_out;

    const int N = in_sizes[0] / K128;   // 40000
    const int E = in_sizes[2];          // 640000
    const int* row = ei;
    const int* col = ei + E;
    const int nb = (N + SC_CHUNK - 1) / SC_CHUNK;

    // ---- workspace carve (256B aligned)
    char* p = (char*)d_ws;
    auto alloc = [&](size_t bytes) -> void* {
        void* r = (void*)p;
        p += (bytes + 255) & ~(size_t)255;
        return r;
    };
    float*     deg   = (float*)    alloc((size_t)N * 4);   // becomes dis in-place
    int*       hist  = (int*)      alloc((size_t)N * 4);
    int*       rs    = (int*)      alloc((size_t)(N + 1) * 4);
    int*       cursor= (int*)      alloc((size_t)N * 4);
    int2*      edata = (int2*)     alloc((size_t)E * 8);
    _Float16*  xw1   = (_Float16*) alloc((size_t)N * 128 * 2);
    _Float16*  h1    = (_Float16*) alloc((size_t)N * 128 * 2);
    _Float16*  xw2   = (_Float16*) alloc((size_t)N * 64 * 2);
    _Float16*  h2    = (_Float16*) alloc((size_t)N * 64 * 2);
    float*     g     = (float*)    alloc(64 * 64 * 4);
    int*       gcnt  = (int*)      alloc(64 * 4);
    int*       bsum  = (int*)      alloc(256 * 4);
    int*       boffs = (int*)      alloc(256 * 4);

    // ---- zero accumulators (ws is poisoned 0xAA before every launch)
    hipMemsetAsync(deg,  0, (size_t)N * 4, stream);
    hipMemsetAsync(hist, 0, (size_t)N * 4, stream);
    hipMemsetAsync(g,    0, 64 * 64 * 4,   stream);
    hipMemsetAsync(gcnt, 0, 64 * 4,        stream);

    // ---- graph preprocessing (shared by both layers)
    k_deg_hist<<<(E + 255) / 256, 256, 0, stream>>>(col, ew, deg, hist, E);
    k_dis<<<(N + 255) / 256, 256, 0, stream>>>(deg, N);
    k_scan_bsum<<<nb, 256, 0, stream>>>(hist, bsum, N);
    k_scan_boffs<<<1, 256, 0, stream>>>(bsum, boffs, rs + N, nb);
    k_scan_apply<<<nb, 256, 0, stream>>>(hist, boffs, rs, cursor, N);
    k_scatter<<<(E + 255) / 256, 256, 0, stream>>>(row, col, ew, deg, cursor, edata, E);

    // ---- layer 1
    k_gemm<128, float><<<(N + 63) / 64, 256, 0, stream>>>(x, W1, xw1, N);
    k_agg<128><<<(N + 7) / 8, 256, 0, stream>>>(xw1, deg, edata, rs, b1, h1, N);

    // ---- layer 2
    k_gemm<64, _Float16><<<(N + 127) / 128, 256, 0, stream>>>(h1, W2, xw2, N);
    k_agg<64><<<(N + 15) / 16, 256, 0, stream>>>(xw2, deg, edata, rs, b2, h2, N);

    // ---- pool + fc
    k_pool<<<(N + POOL_NODES - 1) / POOL_NODES, 256, 0, stream>>>(h2, batch, g, gcnt, N);
    dim3 fcg((FLAT + 255) / 256, NG);
    k_fc<<<fcg, 256, 0, stream>>>(g, gcnt, Wfc, bfc, out);
}

// Round 7
// 270.434 us; speedup vs baseline: 3.0227x; 1.1400x over previous
//
#include <hip/hip_runtime.h>
#include <hip/hip_bf16.h>
#include <hip/hip_fp16.h>
#include <type_traits>

#define NG 64          // number of graphs
#define FLAT 2904      // FC output width
#define K128 128       // inner dim for both GEMMs
#define SC_CHUNK 1024  // scan elements per block

typedef _Float16 h4 __attribute__((ext_vector_type(4)));  // 8B, align 8

// ---------------------------------------------------------------- utilities
__device__ __forceinline__ float4 ld4(const float* p) { return *(const float4*)p; }
__device__ __forceinline__ void st4(float* p, float4 v) { *(float4*)p = v; }
__device__ __forceinline__ float4 ldh4(const _Float16* p) {
    h4 h = *(const h4*)p;
    return make_float4((float)h.x, (float)h.y, (float)h.z, (float)h.w);
}
__device__ __forceinline__ void sth4(_Float16* p, float4 v) {
    h4 h; h.x = (_Float16)v.x; h.y = (_Float16)v.y; h.z = (_Float16)v.z; h.w = (_Float16)v.w;
    *(h4*)p = h;
}

// ------------------------------------------------- degree + hist, ONE u64 atomic/edge
// Memory-side atomic RMWs cost ~32B HBM transactions each (R6: WRITE_SIZE
// 39.8MB = 1.28M atomics x 32B). Pack count (high 24b) + fixed-point ew sum
// (low 40b, scale 2^24) -> halves RMW count. Max deg ~40: sum < 2^30, safe.
__global__ void k_deg_hist(const int* __restrict__ col, const float* __restrict__ ew,
                           unsigned long long* __restrict__ packed, int E) {
    int e = blockIdx.x * blockDim.x + threadIdx.x;
    if (e < E) {
        int c = col[e];
        unsigned long long fx = (unsigned long long)(ew[e] * 16777216.0f + 0.5f);
        atomicAdd(&packed[c], (1ULL << 40) | fx);
    }
}

// unpack: dis = rsqrt(deg + 1), hist = count
__global__ void k_dis(const unsigned long long* __restrict__ packed,
                      float* __restrict__ dis, int* __restrict__ hist, int N) {
    int v = blockIdx.x * blockDim.x + threadIdx.x;
    if (v < N) {
        unsigned long long p = packed[v];
        float deg = (float)(double)(p & ((1ULL << 40) - 1)) * 5.9604644775390625e-8f; // 2^-24
        dis[v]  = rsqrtf(deg + 1.0f);
        hist[v] = (int)(p >> 40);
    }
}

// ------------------------------------------------- multi-block scan (3 kernels)
__global__ __launch_bounds__(256) void k_scan_bsum(const int* __restrict__ hist,
                                                   int* __restrict__ bsum, int N) {
    __shared__ int red[256];
    int tid = threadIdx.x;
    int base = blockIdx.x * SC_CHUNK + tid * 4;
    int s = 0;
    if (base + 4 <= N) {
        int4 v = *(const int4*)(hist + base);
        s = v.x + v.y + v.z + v.w;
    } else {
        for (int i = base; i < N; i++) s += hist[i];
    }
    red[tid] = s;
    __syncthreads();
    for (int off = 128; off > 0; off >>= 1) {
        if (tid < off) red[tid] += red[tid + off];
        __syncthreads();
    }
    if (tid == 0) bsum[blockIdx.x] = red[0];
}

__global__ __launch_bounds__(256) void k_scan_boffs(const int* __restrict__ bsum,
                                                    int* __restrict__ boffs,
                                                    int* __restrict__ rsN, int nb) {
    __shared__ int part[256];
    int tid = threadIdx.x;
    part[tid] = (tid < nb) ? bsum[tid] : 0;
    __syncthreads();
    for (int off = 1; off < 256; off <<= 1) {
        int v = (tid >= off) ? part[tid - off] : 0;
        __syncthreads();
        part[tid] += v;
        __syncthreads();
    }
    if (tid < nb) boffs[tid] = (tid > 0) ? part[tid - 1] : 0;
    if (tid == 255) *rsN = part[255];
}

__global__ __launch_bounds__(256) void k_scan_apply(const int* __restrict__ hist,
                                                    const int* __restrict__ boffs,
                                                    int* __restrict__ rs,
                                                    int* __restrict__ cursor, int N) {
    __shared__ int part[256];
    int tid = threadIdx.x;
    int base = blockIdx.x * SC_CHUNK + tid * 4;
    int4 v = make_int4(0, 0, 0, 0);
    if (base + 4 <= N) v = *(const int4*)(hist + base);
    else for (int i = base; i < N; i++) (&v.x)[i - base] = hist[i];
    int s = v.x + v.y + v.z + v.w;
    part[tid] = s;
    __syncthreads();
    for (int off = 1; off < 256; off <<= 1) {
        int t = (tid >= off) ? part[tid - off] : 0;
        __syncthreads();
        part[tid] += t;
        __syncthreads();
    }
    int run = boffs[blockIdx.x] + part[tid] - s;
    int4 o;
    o.x = run;
    o.y = run + v.x;
    o.z = o.y + v.y;
    o.w = o.z + v.z;
    if (base + 4 <= N) {
        *(int4*)(rs + base) = o;
        *(int4*)(cursor + base) = o;
    } else {
        int vals[4] = {o.x, o.y, o.z, o.w};
        for (int i = base; i < N; i++) { rs[i] = vals[i - base]; cursor[i] = vals[i - base]; }
    }
}

// ------------------------------------------------- scatter: edge-sorted (row,norm) pairs
__global__ void k_scatter(const int* __restrict__ row, const int* __restrict__ col,
                          const float* __restrict__ ew, const float* __restrict__ dis,
                          int* __restrict__ cursor, int2* __restrict__ edata, int E) {
    int e = blockIdx.x * blockDim.x + threadIdx.x;
    if (e < E) {
        int c = col[e], r = row[e];
        float nm = dis[r] * ew[e] * dis[c];
        int pos = atomicAdd(&cursor[c], 1);
        edata[pos] = make_int2(r, __float_as_int(nm));
    }
}

// ------------------------------------------------- fp32 register-tiled GEMM, fp16 out
template <int NCOL, typename AT>
__global__ __launch_bounds__(256) void k_gemm(const AT* __restrict__ A,
                                              const float* __restrict__ W,
                                              _Float16* __restrict__ out, int M) {
    constexpr int JG   = NCOL / 4;
    constexpr int RG   = 256 / JG;
    constexpr int RPT  = 8;
    constexpr int ROWS = RG * RPT;
    constexpr int KC   = 32;
    constexpr int AS   = KC + 4;

    __shared__ float As[ROWS * AS];
    __shared__ float Ws[KC * NCOL];

    int tid = threadIdx.x;
    int tx  = tid % JG;
    int ty  = tid / JG;
    int row0 = blockIdx.x * ROWS;

    float4 acc[RPT];
#pragma unroll
    for (int i = 0; i < RPT; i++) acc[i] = make_float4(0.f, 0.f, 0.f, 0.f);

    for (int kc = 0; kc < K128; kc += KC) {
#pragma unroll
        for (int q = 0; q < ROWS * 8 / 256; q++) {
            int idx = tid + 256 * q;
            int r   = idx >> 3;
            int f4  = (idx & 7) * 4;
            int gr  = row0 + r; if (gr >= M) gr = M - 1;
            float4 v;
            if constexpr (std::is_same_v<AT, float>) v = ld4(A + (size_t)gr * K128 + kc + f4);
            else                                     v = ldh4(A + (size_t)gr * K128 + kc + f4);
            st4(&As[r * AS + f4], v);
        }
#pragma unroll
        for (int q = 0; q < KC * NCOL / 4 / 256; q++) {
            int idx = (tid + 256 * q) * 4;
            st4(&Ws[idx], ld4(W + (size_t)kc * NCOL + idx));
        }
        __syncthreads();

#pragma unroll
        for (int k4 = 0; k4 < KC; k4 += 4) {
            float4 w0 = ld4(&Ws[(k4 + 0) * NCOL + tx * 4]);
            float4 w1 = ld4(&Ws[(k4 + 1) * NCOL + tx * 4]);
            float4 w2 = ld4(&Ws[(k4 + 2) * NCOL + tx * 4]);
            float4 w3 = ld4(&Ws[(k4 + 3) * NCOL + tx * 4]);
#pragma unroll
            for (int i = 0; i < RPT; i++) {
                float4 a = ld4(&As[(ty + RG * i) * AS + k4]);
                acc[i].x += a.x * w0.x; acc[i].y += a.x * w0.y;
                acc[i].z += a.x * w0.z; acc[i].w += a.x * w0.w;
                acc[i].x += a.y * w1.x; acc[i].y += a.y * w1.y;
                acc[i].z += a.y * w1.z; acc[i].w += a.y * w1.w;
                acc[i].x += a.z * w2.x; acc[i].y += a.z * w2.y;
                acc[i].z += a.z * w2.z; acc[i].w += a.z * w2.w;
                acc[i].x += a.w * w3.x; acc[i].y += a.w * w3.y;
                acc[i].z += a.w * w3.z; acc[i].w += a.w * w3.w;
            }
        }
        __syncthreads();
    }

#pragma unroll
    for (int i = 0; i < RPT; i++) {
        int r = row0 + ty + RG * i;
        if (r < M) sth4(out + (size_t)r * NCOL + tx * 4, acc[i]);
    }
}

// ------------------------------------------------- CSR gather agg, 4-way ILP
template <int F>
__global__ __launch_bounds__(256) void k_agg(const _Float16* __restrict__ xw,
                                             const float* __restrict__ dis,
                                             const int2* __restrict__ edata,
                                             const int* __restrict__ rs,
                                             const float* __restrict__ bias,
                                             _Float16* __restrict__ out, int N) {
    constexpr int TPN = F / 4;
    constexpr int NPB = 256 / TPN;
    int node = blockIdx.x * NPB + threadIdx.x / TPN;
    int j4   = (threadIdx.x % TPN) * 4;
    if (node >= N) return;
    float dv = dis[node];
    float sw = dv * dv;
    float4 self = ldh4(xw + (size_t)node * F + j4);
    float4 bv   = ld4(bias + j4);
    float4 a0, a1, a2, a3;
    a0.x = self.x * sw + bv.x;
    a0.y = self.y * sw + bv.y;
    a0.z = self.z * sw + bv.z;
    a0.w = self.w * sw + bv.w;
    a1 = make_float4(0.f, 0.f, 0.f, 0.f);
    a2 = a1; a3 = a1;
    int s = rs[node], e = rs[node + 1];
    int j = s;
    for (; j + 4 <= e; j += 4) {
        int2 q0 = edata[j + 0];
        int2 q1 = edata[j + 1];
        int2 q2 = edata[j + 2];
        int2 q3 = edata[j + 3];
        float4 v0 = ldh4(xw + (size_t)q0.x * F + j4);
        float4 v1 = ldh4(xw + (size_t)q1.x * F + j4);
        float4 v2 = ldh4(xw + (size_t)q2.x * F + j4);
        float4 v3 = ldh4(xw + (size_t)q3.x * F + j4);
        float n0 = __int_as_float(q0.y), n1 = __int_as_float(q1.y);
        float n2 = __int_as_float(q2.y), n3 = __int_as_float(q3.y);
        a0.x += n0 * v0.x; a0.y += n0 * v0.y; a0.z += n0 * v0.z; a0.w += n0 * v0.w;
        a1.x += n1 * v1.x; a1.y += n1 * v1.y; a1.z += n1 * v1.z; a1.w += n1 * v1.w;
        a2.x += n2 * v2.x; a2.y += n2 * v2.y; a2.z += n2 * v2.z; a2.w += n2 * v2.w;
        a3.x += n3 * v3.x; a3.y += n3 * v3.y; a3.z += n3 * v3.z; a3.w += n3 * v3.w;
    }
    for (; j < e; j++) {
        int2 q = edata[j];
        float nm = __int_as_float(q.y);
        float4 v = ldh4(xw + (size_t)q.x * F + j4);
        a0.x += nm * v.x; a0.y += nm * v.y; a0.z += nm * v.z; a0.w += nm * v.w;
    }
    float4 acc;
    acc.x = (a0.x + a1.x) + (a2.x + a3.x);
    acc.y = (a0.y + a1.y) + (a2.y + a3.y);
    acc.z = (a0.z + a1.z) + (a2.z + a3.z);
    acc.w = (a0.w + a1.w) + (a2.w + a3.w);
    acc.x = fmaxf(acc.x, 0.f); acc.y = fmaxf(acc.y, 0.f);
    acc.z = fmaxf(acc.z, 0.f); acc.w = fmaxf(acc.w, 0.f);
    sth4(out + (size_t)node * F + j4, acc);
}

// ------------------------------------------------- mean-pool accumulate (sorted batch)
#define POOL_NODES 256
__global__ __launch_bounds__(256) void k_pool(const _Float16* __restrict__ h,
                                              const int* __restrict__ batch,
                                              float* __restrict__ g, int* __restrict__ gcnt,
                                              int N) {
    int base  = blockIdx.x * POOL_NODES;
    int f     = threadIdx.x & 63;
    int slice = threadIdx.x >> 6;
    int lim   = base + POOL_NODES; if (lim > N) lim = N;
    float acc = 0.f;
    int cur = -1, cnt = 0;
    for (int i = base + slice; i < lim; i += 4) {
        int b = batch[i];
        if (b != cur) {
            if (cur >= 0) {
                atomicAdd(&g[cur * 64 + f], acc);
                if (f == 0) atomicAdd(&gcnt[cur], cnt);
            }
            cur = b; acc = 0.f; cnt = 0;
        }
        acc += (float)h[(size_t)i * 64 + f];
        cnt++;
    }
    if (cur >= 0) {
        atomicAdd(&g[cur * 64 + f], acc);
        if (f == 0) atomicAdd(&gcnt[cur], cnt);
    }
}

// ------------------------------------------------- FC: out[NG,FLAT] = (g/cnt) @ Wfc + bfc
__global__ __launch_bounds__(256) void k_fc(const float* __restrict__ g,
                                            const int* __restrict__ gcnt,
                                            const float* __restrict__ Wfc,
                                            const float* __restrict__ bfc,
                                            float* __restrict__ out) {
    __shared__ float gs[64];
    int i = blockIdx.y;
    int j = blockIdx.x * blockDim.x + threadIdx.x;
    if (threadIdx.x < 64) {
        float c = (float)gcnt[i];
        gs[threadIdx.x] = g[i * 64 + threadIdx.x] / fmaxf(c, 1.0f);
    }
    __syncthreads();
    if (j >= FLAT) return;
    float acc = bfc[j];
#pragma unroll 8
    for (int k = 0; k < 64; k++) acc += gs[k] * Wfc[k * FLAT + j];
    out[(size_t)i * FLAT + j] = acc;
}

// ================================================================ launcher
extern "C" void kernel_launch(void* const* d_in, const int* in_sizes, int n_in,
                              void* d_out, int out_size, void* d_ws, size_t ws_size,
                              hipStream_t stream) {
    const float* x    = (const float*)d_in[0];
    const int*   ei   = (const int*)d_in[1];
    const float* ew   = (const float*)d_in[2];
    const int*   batch= (const int*)d_in[3];
    const float* W1   = (const float*)d_in[4];
    const float* b1   = (const float*)d_in[5];
    const float* W2   = (const float*)d_in[6];
    const float* b2   = (const float*)d_in[7];
    const float* Wfc  = (const float*)d_in[8];
    const float* bfc  = (const float*)d_in[9];
    float* out = (float*)d_out;

    const int N = in_sizes[0] / K128;   // 40000
    const int E = in_sizes[2];          // 640000
    const int* row = ei;
    const int* col = ei + E;
    const int nb = (N + SC_CHUNK - 1) / SC_CHUNK;

    // ---- workspace carve (256B aligned)
    char* p = (char*)d_ws;
    auto alloc = [&](size_t bytes) -> void* {
        void* r = (void*)p;
        p += (bytes + 255) & ~(size_t)255;
        return r;
    };
    unsigned long long* packed = (unsigned long long*)alloc((size_t)N * 8);
    float*     dis   = (float*)    alloc((size_t)N * 4);
    int*       hist  = (int*)      alloc((size_t)N * 4);
    int*       rs    = (int*)      alloc((size_t)(N + 1) * 4);
    int*       cursor= (int*)      alloc((size_t)N * 4);
    int2*      edata = (int2*)     alloc((size_t)E * 8);
    _Float16*  xw1   = (_Float16*) alloc((size_t)N * 128 * 2);
    _Float16*  h1    = (_Float16*) alloc((size_t)N * 128 * 2);
    _Float16*  xw2   = (_Float16*) alloc((size_t)N * 64 * 2);
    _Float16*  h2    = (_Float16*) alloc((size_t)N * 64 * 2);
    float*     g     = (float*)    alloc(64 * 64 * 4);
    int*       gcnt  = (int*)      alloc(64 * 4);
    int*       bsum  = (int*)      alloc(256 * 4);
    int*       boffs = (int*)      alloc(256 * 4);

    // ---- zero accumulators (ws is poisoned 0xAA before every launch)
    hipMemsetAsync(packed, 0, (size_t)N * 8, stream);
    hipMemsetAsync(g,      0, 64 * 64 * 4,   stream);
    hipMemsetAsync(gcnt,   0, 64 * 4,        stream);

    // ---- graph preprocessing (shared by both layers)
    k_deg_hist<<<(E + 255) / 256, 256, 0, stream>>>(col, ew, packed, E);
    k_dis<<<(N + 255) / 256, 256, 0, stream>>>(packed, dis, hist, N);
    k_scan_bsum<<<nb, 256, 0, stream>>>(hist, bsum, N);
    k_scan_boffs<<<1, 256, 0, stream>>>(bsum, boffs, rs + N, nb);
    k_scan_apply<<<nb, 256, 0, stream>>>(hist, boffs, rs, cursor, N);
    k_scatter<<<(E + 255) / 256, 256, 0, stream>>>(row, col, ew, dis, cursor, edata, E);

    // ---- layer 1
    k_gemm<128, float><<<(N + 63) / 64, 256, 0, stream>>>(x, W1, xw1, N);
    k_agg<128><<<(N + 7) / 8, 256, 0, stream>>>(xw1, dis, edata, rs, b1, h1, N);

    // ---- layer 2
    k_gemm<64, _Float16><<<(N + 127) / 128, 256, 0, stream>>>(h1, W2, xw2, N);
    k_agg<64><<<(N + 15) / 16, 256, 0, stream>>>(xw2, dis, edata, rs, b2, h2, N);

    // ---- pool + fc
    k_pool<<<(N + POOL_NODES - 1) / POOL_NODES, 256, 0, stream>>>(h2, batch, g, gcnt, N);
    dim3 fcg((FLAT + 255) / 256, NG);
    k_fc<<<fcg, 256, 0, stream>>>(g, gcnt, Wfc, bfc, out);
}

// Round 8
// 248.622 us; speedup vs baseline: 3.2879x; 1.0877x over previous
//
#include <hip/hip_runtime.h>
#include <hip/hip_bf16.h>
#include <hip/hip_fp16.h>
#include <type_traits>

#define NG 64          // number of graphs
#define FLAT 2904      // FC output width
#define K128 128       // inner dim for both GEMMs
#define BKB 256        // cols per bucket (col >> 8)

typedef _Float16 h4 __attribute__((ext_vector_type(4)));  // 8B, align 8

// ---------------------------------------------------------------- utilities
__device__ __forceinline__ float4 ld4(const float* p) { return *(const float4*)p; }
__device__ __forceinline__ void st4(float* p, float4 v) { *(float4*)p = v; }
__device__ __forceinline__ float4 ldh4(const _Float16* p) {
    h4 h = *(const h4*)p;
    return make_float4((float)h.x, (float)h.y, (float)h.z, (float)h.w);
}
__device__ __forceinline__ void sth4(_Float16* p, float4 v) {
    h4 h; h.x = (_Float16)v.x; h.y = (_Float16)v.y; h.z = (_Float16)v.z; h.w = (_Float16)v.w;
    *(h4*)p = h;
}

// ================================================================ CSR build:
// two-level bucket counting sort. Replaces per-edge global atomics (R6/R7
// showed each random atomic RMW costs ~32B memory-side traffic; deg_hist +
// scatter burned ~85MB of RMW). Bucket = col>>8 (157 buckets x 256 cols).

// ---- A1: global bucket histogram, LDS-privatized (only ~nbk atomics/block)
__global__ __launch_bounds__(256) void k_bhist(const int* __restrict__ col,
                                               int* __restrict__ bhist, int E, int nbk) {
    __shared__ int h[BKB];
    int tid = threadIdx.x;
    for (int i = tid; i < nbk; i += 256) h[i] = 0;
    __syncthreads();
    int base = blockIdx.x * 1024 + tid * 4;
#pragma unroll
    for (int q = 0; q < 4; q++) {
        int e = base + q;
        if (e < E) atomicAdd(&h[col[e] >> 8], 1);
    }
    __syncthreads();
    for (int i = tid; i < nbk; i += 256) if (h[i]) atomicAdd(&bhist[i], h[i]);
}

// ---- A2: scan bucket counts -> bases + cursors; rs[N] = E
__global__ __launch_bounds__(256) void k_bscan(const int* __restrict__ bhist,
                                               int* __restrict__ bbase,
                                               int* __restrict__ bcursor,
                                               int* __restrict__ rsN, int E, int nbk) {
    __shared__ int part[256];
    int tid = threadIdx.x;
    int v = (tid < nbk) ? bhist[tid] : 0;
    part[tid] = v;
    __syncthreads();
    for (int off = 1; off < 256; off <<= 1) {
        int t = (tid >= off) ? part[tid - off] : 0;
        __syncthreads();
        part[tid] += t;
        __syncthreads();
    }
    if (tid < nbk) { int ex = part[tid] - v; bbase[tid] = ex; bcursor[tid] = ex; }
    if (tid == nbk - 1) bbase[nbk] = part[tid];
    if (tid == 0) *rsN = E;
}

// ---- A3: partition edges into buckets. Per-block LDS hist -> one global
// reservation atomic per bucket per block -> ~4-edge contiguous write runs.
// Payload packs (col<<16)|row (both < 65536) + ew bits: 8B.
__global__ __launch_bounds__(256) void k_bucket(const int* __restrict__ row,
                                                const int* __restrict__ col,
                                                const float* __restrict__ ew,
                                                int* __restrict__ bcursor,
                                                uint2* __restrict__ bk, int E, int nbk) {
    __shared__ int h[BKB];
    __shared__ int cur[BKB];
    int tid = threadIdx.x;
    for (int i = tid; i < nbk; i += 256) h[i] = 0;
    __syncthreads();
    int base = blockIdx.x * 1024 + tid * 4;
    int c[4];
#pragma unroll
    for (int q = 0; q < 4; q++) {
        int e = base + q;
        c[q] = (e < E) ? col[e] : -1;
        if (c[q] >= 0) atomicAdd(&h[c[q] >> 8], 1);
    }
    __syncthreads();
    for (int i = tid; i < nbk; i += 256) cur[i] = h[i] ? atomicAdd(&bcursor[i], h[i]) : 0;
    __syncthreads();
#pragma unroll
    for (int q = 0; q < 4; q++) {
        int e = base + q;
        if (c[q] >= 0) {
            int slot = atomicAdd(&cur[c[q] >> 8], 1);
            bk[slot] = make_uint2(((unsigned)c[q] << 16) | (unsigned)row[e],
                                  __float_as_uint(ew[e]));
        }
    }
}

// ---- B1: per bucket, weighted degree + count via LDS atomics -> dis, rs.
// Replaces global deg_hist atomics AND the 3-kernel scan over N.
__global__ __launch_bounds__(256) void k_cols(const uint2* __restrict__ bk,
                                              const int* __restrict__ bbase,
                                              float* __restrict__ dis,
                                              int* __restrict__ rs, int N) {
    __shared__ float sdeg[BKB];
    __shared__ int scnt[BKB];
    __shared__ int part[BKB];
    int b = blockIdx.x, tid = threadIdx.x;
    sdeg[tid] = 0.f; scnt[tid] = 0;
    __syncthreads();
    int s = bbase[b], e = bbase[b + 1];
    for (int i = s + tid; i < e; i += 256) {
        uint2 q = bk[i];
        int c8 = (q.x >> 16) & 255;
        atomicAdd(&sdeg[c8], __uint_as_float(q.y));
        atomicAdd(&scnt[c8], 1);
    }
    __syncthreads();
    int cnt = scnt[tid];
    part[tid] = cnt;
    __syncthreads();
    for (int off = 1; off < 256; off <<= 1) {
        int t = (tid >= off) ? part[tid - off] : 0;
        __syncthreads();
        part[tid] += t;
        __syncthreads();
    }
    int gcol = b * BKB + tid;
    if (gcol < N) {
        dis[gcol] = rsqrtf(sdeg[tid] + 1.0f);
        rs[gcol]  = s + part[tid] - cnt;
    }
}

// ---- B2: per bucket, compute norm + place edges colwise-contiguous (CSR).
// dis[row] reads hit L2 (160KB table); edata writes are col-run coalesced.
__global__ __launch_bounds__(256) void k_edata(const uint2* __restrict__ bk,
                                               const int* __restrict__ bbase,
                                               const float* __restrict__ dis,
                                               const int* __restrict__ rs,
                                               int2* __restrict__ edata, int N) {
    __shared__ int cur[BKB];
    __shared__ float sdis[BKB];
    int b = blockIdx.x, tid = threadIdx.x;
    int gcol = b * BKB + tid;
    cur[tid]  = (gcol < N) ? rs[gcol] : 0;
    sdis[tid] = (gcol < N) ? dis[gcol] : 0.f;
    __syncthreads();
    int s = bbase[b], e = bbase[b + 1];
    for (int i = s + tid; i < e; i += 256) {
        uint2 q = bk[i];
        int c8 = (q.x >> 16) & 255;
        int r  = q.x & 0xFFFF;
        float nm = dis[r] * __uint_as_float(q.y) * sdis[c8];
        int pos = atomicAdd(&cur[c8], 1);
        edata[pos] = make_int2(r, __float_as_int(nm));
    }
}

// ------------------------------------------------- fp32 register-tiled GEMM, fp16 out
template <int NCOL, typename AT>
__global__ __launch_bounds__(256) void k_gemm(const AT* __restrict__ A,
                                              const float* __restrict__ W,
                                              _Float16* __restrict__ out, int M) {
    constexpr int JG   = NCOL / 4;
    constexpr int RG   = 256 / JG;
    constexpr int RPT  = 8;
    constexpr int ROWS = RG * RPT;
    constexpr int KC   = 32;
    constexpr int AS   = KC + 4;

    __shared__ float As[ROWS * AS];
    __shared__ float Ws[KC * NCOL];

    int tid = threadIdx.x;
    int tx  = tid % JG;
    int ty  = tid / JG;
    int row0 = blockIdx.x * ROWS;

    float4 acc[RPT];
#pragma unroll
    for (int i = 0; i < RPT; i++) acc[i] = make_float4(0.f, 0.f, 0.f, 0.f);

    for (int kc = 0; kc < K128; kc += KC) {
#pragma unroll
        for (int q = 0; q < ROWS * 8 / 256; q++) {
            int idx = tid + 256 * q;
            int r   = idx >> 3;
            int f4  = (idx & 7) * 4;
            int gr  = row0 + r; if (gr >= M) gr = M - 1;
            float4 v;
            if constexpr (std::is_same_v<AT, float>) v = ld4(A + (size_t)gr * K128 + kc + f4);
            else                                     v = ldh4(A + (size_t)gr * K128 + kc + f4);
            st4(&As[r * AS + f4], v);
        }
#pragma unroll
        for (int q = 0; q < KC * NCOL / 4 / 256; q++) {
            int idx = (tid + 256 * q) * 4;
            st4(&Ws[idx], ld4(W + (size_t)kc * NCOL + idx));
        }
        __syncthreads();

#pragma unroll
        for (int k4 = 0; k4 < KC; k4 += 4) {
            float4 w0 = ld4(&Ws[(k4 + 0) * NCOL + tx * 4]);
            float4 w1 = ld4(&Ws[(k4 + 1) * NCOL + tx * 4]);
            float4 w2 = ld4(&Ws[(k4 + 2) * NCOL + tx * 4]);
            float4 w3 = ld4(&Ws[(k4 + 3) * NCOL + tx * 4]);
#pragma unroll
            for (int i = 0; i < RPT; i++) {
                float4 a = ld4(&As[(ty + RG * i) * AS + k4]);
                acc[i].x += a.x * w0.x; acc[i].y += a.x * w0.y;
                acc[i].z += a.x * w0.z; acc[i].w += a.x * w0.w;
                acc[i].x += a.y * w1.x; acc[i].y += a.y * w1.y;
                acc[i].z += a.y * w1.z; acc[i].w += a.y * w1.w;
                acc[i].x += a.z * w2.x; acc[i].y += a.z * w2.y;
                acc[i].z += a.z * w2.z; acc[i].w += a.z * w2.w;
                acc[i].x += a.w * w3.x; acc[i].y += a.w * w3.y;
                acc[i].z += a.w * w3.z; acc[i].w += a.w * w3.w;
            }
        }
        __syncthreads();
    }

#pragma unroll
    for (int i = 0; i < RPT; i++) {
        int r = row0 + ty + RG * i;
        if (r < M) sth4(out + (size_t)r * NCOL + tx * 4, acc[i]);
    }
}

// ------------------------------------------------- CSR gather agg, 4-way ILP
template <int F>
__global__ __launch_bounds__(256) void k_agg(const _Float16* __restrict__ xw,
                                             const float* __restrict__ dis,
                                             const int2* __restrict__ edata,
                                             const int* __restrict__ rs,
                                             const float* __restrict__ bias,
                                             _Float16* __restrict__ out, int N) {
    constexpr int TPN = F / 4;
    constexpr int NPB = 256 / TPN;
    int node = blockIdx.x * NPB + threadIdx.x / TPN;
    int j4   = (threadIdx.x % TPN) * 4;
    if (node >= N) return;
    float dv = dis[node];
    float sw = dv * dv;
    float4 self = ldh4(xw + (size_t)node * F + j4);
    float4 bv   = ld4(bias + j4);
    float4 a0, a1, a2, a3;
    a0.x = self.x * sw + bv.x;
    a0.y = self.y * sw + bv.y;
    a0.z = self.z * sw + bv.z;
    a0.w = self.w * sw + bv.w;
    a1 = make_float4(0.f, 0.f, 0.f, 0.f);
    a2 = a1; a3 = a1;
    int s = rs[node], e = rs[node + 1];
    int j = s;
    for (; j + 4 <= e; j += 4) {
        int2 q0 = edata[j + 0];
        int2 q1 = edata[j + 1];
        int2 q2 = edata[j + 2];
        int2 q3 = edata[j + 3];
        float4 v0 = ldh4(xw + (size_t)q0.x * F + j4);
        float4 v1 = ldh4(xw + (size_t)q1.x * F + j4);
        float4 v2 = ldh4(xw + (size_t)q2.x * F + j4);
        float4 v3 = ldh4(xw + (size_t)q3.x * F + j4);
        float n0 = __int_as_float(q0.y), n1 = __int_as_float(q1.y);
        float n2 = __int_as_float(q2.y), n3 = __int_as_float(q3.y);
        a0.x += n0 * v0.x; a0.y += n0 * v0.y; a0.z += n0 * v0.z; a0.w += n0 * v0.w;
        a1.x += n1 * v1.x; a1.y += n1 * v1.y; a1.z += n1 * v1.z; a1.w += n1 * v1.w;
        a2.x += n2 * v2.x; a2.y += n2 * v2.y; a2.z += n2 * v2.z; a2.w += n2 * v2.w;
        a3.x += n3 * v3.x; a3.y += n3 * v3.y; a3.z += n3 * v3.z; a3.w += n3 * v3.w;
    }
    for (; j < e; j++) {
        int2 q = edata[j];
        float nm = __int_as_float(q.y);
        float4 v = ldh4(xw + (size_t)q.x * F + j4);
        a0.x += nm * v.x; a0.y += nm * v.y; a0.z += nm * v.z; a0.w += nm * v.w;
    }
    float4 acc;
    acc.x = (a0.x + a1.x) + (a2.x + a3.x);
    acc.y = (a0.y + a1.y) + (a2.y + a3.y);
    acc.z = (a0.z + a1.z) + (a2.z + a3.z);
    acc.w = (a0.w + a1.w) + (a2.w + a3.w);
    acc.x = fmaxf(acc.x, 0.f); acc.y = fmaxf(acc.y, 0.f);
    acc.z = fmaxf(acc.z, 0.f); acc.w = fmaxf(acc.w, 0.f);
    sth4(out + (size_t)node * F + j4, acc);
}

// ------------------------------------------------- mean-pool accumulate (sorted batch)
#define POOL_NODES 256
__global__ __launch_bounds__(256) void k_pool(const _Float16* __restrict__ h,
                                              const int* __restrict__ batch,
                                              float* __restrict__ g, int* __restrict__ gcnt,
                                              int N) {
    int base  = blockIdx.x * POOL_NODES;
    int f     = threadIdx.x & 63;
    int slice = threadIdx.x >> 6;
    int lim   = base + POOL_NODES; if (lim > N) lim = N;
    float acc = 0.f;
    int cur = -1, cnt = 0;
    for (int i = base + slice; i < lim; i += 4) {
        int b = batch[i];
        if (b != cur) {
            if (cur >= 0) {
                atomicAdd(&g[cur * 64 + f], acc);
                if (f == 0) atomicAdd(&gcnt[cur], cnt);
            }
            cur = b; acc = 0.f; cnt = 0;
        }
        acc += (float)h[(size_t)i * 64 + f];
        cnt++;
    }
    if (cur >= 0) {
        atomicAdd(&g[cur * 64 + f], acc);
        if (f == 0) atomicAdd(&gcnt[cur], cnt);
    }
}

// ------------------------------------------------- FC: out[NG,FLAT] = (g/cnt) @ Wfc + bfc
__global__ __launch_bounds__(256) void k_fc(const float* __restrict__ g,
                                            const int* __restrict__ gcnt,
                                            const float* __restrict__ Wfc,
                                            const float* __restrict__ bfc,
                                            float* __restrict__ out) {
    __shared__ float gs[64];
    int i = blockIdx.y;
    int j = blockIdx.x * blockDim.x + threadIdx.x;
    if (threadIdx.x < 64) {
        float c = (float)gcnt[i];
        gs[threadIdx.x] = g[i * 64 + threadIdx.x] / fmaxf(c, 1.0f);
    }
    __syncthreads();
    if (j >= FLAT) return;
    float acc = bfc[j];
#pragma unroll 8
    for (int k = 0; k < 64; k++) acc += gs[k] * Wfc[k * FLAT + j];
    out[(size_t)i * FLAT + j] = acc;
}

// ================================================================ launcher
extern "C" void kernel_launch(void* const* d_in, const int* in_sizes, int n_in,
                              void* d_out, int out_size, void* d_ws, size_t ws_size,
                              hipStream_t stream) {
    const float* x    = (const float*)d_in[0];
    const int*   ei   = (const int*)d_in[1];
    const float* ew   = (const float*)d_in[2];
    const int*   batch= (const int*)d_in[3];
    const float* W1   = (const float*)d_in[4];
    const float* b1   = (const float*)d_in[5];
    const float* W2   = (const float*)d_in[6];
    const float* b2   = (const float*)d_in[7];
    const float* Wfc  = (const float*)d_in[8];
    const float* bfc  = (const float*)d_in[9];
    float* out = (float*)d_out;

    const int N = in_sizes[0] / K128;   // 40000
    const int E = in_sizes[2];          // 640000
    const int* row = ei;
    const int* col = ei + E;
    const int nbk = (N + BKB - 1) / BKB;   // 157 buckets
    const int neb = (E + 1023) / 1024;     // edge-chunk blocks

    // ---- workspace carve (256B aligned)
    char* p = (char*)d_ws;
    auto alloc = [&](size_t bytes) -> void* {
        void* r = (void*)p;
        p += (bytes + 255) & ~(size_t)255;
        return r;
    };
    float*     dis   = (float*)    alloc((size_t)N * 4);
    int*       rs    = (int*)      alloc((size_t)(N + 1) * 4);
    uint2*     bk    = (uint2*)    alloc((size_t)E * 8);
    int2*      edata = (int2*)     alloc((size_t)E * 8);
    _Float16*  xw1   = (_Float16*) alloc((size_t)N * 128 * 2);
    _Float16*  h1    = (_Float16*) alloc((size_t)N * 128 * 2);
    _Float16*  xw2   = (_Float16*) alloc((size_t)N * 64 * 2);
    _Float16*  h2    = (_Float16*) alloc((size_t)N * 64 * 2);
    float*     g     = (float*)    alloc(64 * 64 * 4);
    int*       gcnt  = (int*)      alloc(64 * 4);
    int*       bhist = (int*)      alloc(BKB * 4);
    int*       bbase = (int*)      alloc((BKB + 2) * 4);
    int*       bcur  = (int*)      alloc(BKB * 4);

    // ---- zero accumulators (ws is poisoned 0xAA before every launch)
    hipMemsetAsync(bhist, 0, BKB * 4,     stream);
    hipMemsetAsync(g,     0, 64 * 64 * 4, stream);
    hipMemsetAsync(gcnt,  0, 64 * 4,      stream);

    // ---- CSR build (bucket counting sort, shared by both layers)
    k_bhist <<<neb, 256, 0, stream>>>(col, bhist, E, nbk);
    k_bscan <<<1,   256, 0, stream>>>(bhist, bbase, bcur, rs + N, E, nbk);
    k_bucket<<<neb, 256, 0, stream>>>(row, col, ew, bcur, bk, E, nbk);
    k_cols  <<<nbk, 256, 0, stream>>>(bk, bbase, dis, rs, N);
    k_edata <<<nbk, 256, 0, stream>>>(bk, bbase, dis, rs, edata, N);

    // ---- layer 1
    k_gemm<128, float><<<(N + 63) / 64, 256, 0, stream>>>(x, W1, xw1, N);
    k_agg<128><<<(N + 7) / 8, 256, 0, stream>>>(xw1, dis, edata, rs, b1, h1, N);

    // ---- layer 2
    k_gemm<64, _Float16><<<(N + 127) / 128, 256, 0, stream>>>(h1, W2, xw2, N);
    k_agg<64><<<(N + 15) / 16, 256, 0, stream>>>(xw2, dis, edata, rs, b2, h2, N);

    // ---- pool + fc
    k_pool<<<(N + POOL_NODES - 1) / POOL_NODES, 256, 0, stream>>>(h2, batch, g, gcnt, N);
    dim3 fcg((FLAT + 255) / 256, NG);
    k_fc<<<fcg, 256, 0, stream>>>(g, gcnt, Wfc, bfc, out);
}

// Round 9
// 227.906 us; speedup vs baseline: 3.5867x; 1.0909x over previous
//
#include <hip/hip_runtime.h>
#include <hip/hip_bf16.h>
#include <hip/hip_fp16.h>
#include <type_traits>

#define NG 64          // number of graphs
#define FLAT 2904      // FC output width
#define K128 128       // inner dim for both GEMMs
#define BKB 256        // cols per bucket (col >> 8)

typedef _Float16 h4 __attribute__((ext_vector_type(4)));  // 8B
typedef _Float16 half8 __attribute__((ext_vector_type(8)));  // 16B MFMA frag
typedef float f32x4 __attribute__((ext_vector_type(4)));

// ---------------------------------------------------------------- utilities
__device__ __forceinline__ float4 ld4(const float* p) { return *(const float4*)p; }
__device__ __forceinline__ void st4(float* p, float4 v) { *(float4*)p = v; }
__device__ __forceinline__ float4 ldh4(const _Float16* p) {
    h4 h = *(const h4*)p;
    return make_float4((float)h.x, (float)h.y, (float)h.z, (float)h.w);
}
__device__ __forceinline__ void sth4(_Float16* p, float4 v) {
    h4 h; h.x = (_Float16)v.x; h.y = (_Float16)v.y; h.z = (_Float16)v.z; h.w = (_Float16)v.w;
    *(h4*)p = h;
}

// ================================================================ CSR build
// (bucket counting sort — see R7 notes; atomic RMW traffic ~8MB vs 85MB)

__global__ __launch_bounds__(256) void k_bhist(const int* __restrict__ col,
                                               int* __restrict__ bhist, int E, int nbk) {
    __shared__ int h[BKB];
    int tid = threadIdx.x;
    for (int i = tid; i < nbk; i += 256) h[i] = 0;
    __syncthreads();
    int base = blockIdx.x * 1024 + tid * 4;
#pragma unroll
    for (int q = 0; q < 4; q++) {
        int e = base + q;
        if (e < E) atomicAdd(&h[col[e] >> 8], 1);
    }
    __syncthreads();
    for (int i = tid; i < nbk; i += 256) if (h[i]) atomicAdd(&bhist[i], h[i]);
}

__global__ __launch_bounds__(256) void k_bscan(const int* __restrict__ bhist,
                                               int* __restrict__ bbase,
                                               int* __restrict__ bcursor,
                                               int* __restrict__ rsN, int E, int nbk) {
    __shared__ int part[256];
    int tid = threadIdx.x;
    int v = (tid < nbk) ? bhist[tid] : 0;
    part[tid] = v;
    __syncthreads();
    for (int off = 1; off < 256; off <<= 1) {
        int t = (tid >= off) ? part[tid - off] : 0;
        __syncthreads();
        part[tid] += t;
        __syncthreads();
    }
    if (tid < nbk) { int ex = part[tid] - v; bbase[tid] = ex; bcursor[tid] = ex; }
    if (tid == nbk - 1) bbase[nbk] = part[tid];
    if (tid == 0) *rsN = E;
}

__global__ __launch_bounds__(256) void k_bucket(const int* __restrict__ row,
                                                const int* __restrict__ col,
                                                const float* __restrict__ ew,
                                                int* __restrict__ bcursor,
                                                uint2* __restrict__ bk, int E, int nbk) {
    __shared__ int h[BKB];
    __shared__ int cur[BKB];
    int tid = threadIdx.x;
    for (int i = tid; i < nbk; i += 256) h[i] = 0;
    __syncthreads();
    int base = blockIdx.x * 1024 + tid * 4;
    int c[4];
#pragma unroll
    for (int q = 0; q < 4; q++) {
        int e = base + q;
        c[q] = (e < E) ? col[e] : -1;
        if (c[q] >= 0) atomicAdd(&h[c[q] >> 8], 1);
    }
    __syncthreads();
    for (int i = tid; i < nbk; i += 256) cur[i] = h[i] ? atomicAdd(&bcursor[i], h[i]) : 0;
    __syncthreads();
#pragma unroll
    for (int q = 0; q < 4; q++) {
        int e = base + q;
        if (c[q] >= 0) {
            int slot = atomicAdd(&cur[c[q] >> 8], 1);
            bk[slot] = make_uint2(((unsigned)c[q] << 16) | (unsigned)row[e],
                                  __float_as_uint(ew[e]));
        }
    }
}

__global__ __launch_bounds__(256) void k_cols(const uint2* __restrict__ bk,
                                              const int* __restrict__ bbase,
                                              float* __restrict__ dis,
                                              int* __restrict__ rs, int N) {
    __shared__ float sdeg[BKB];
    __shared__ int scnt[BKB];
    __shared__ int part[BKB];
    int b = blockIdx.x, tid = threadIdx.x;
    sdeg[tid] = 0.f; scnt[tid] = 0;
    __syncthreads();
    int s = bbase[b], e = bbase[b + 1];
    for (int i = s + tid; i < e; i += 256) {
        uint2 q = bk[i];
        int c8 = (q.x >> 16) & 255;
        atomicAdd(&sdeg[c8], __uint_as_float(q.y));
        atomicAdd(&scnt[c8], 1);
    }
    __syncthreads();
    int cnt = scnt[tid];
    part[tid] = cnt;
    __syncthreads();
    for (int off = 1; off < 256; off <<= 1) {
        int t = (tid >= off) ? part[tid - off] : 0;
        __syncthreads();
        part[tid] += t;
        __syncthreads();
    }
    int gcol = b * BKB + tid;
    if (gcol < N) {
        dis[gcol] = rsqrtf(sdeg[tid] + 1.0f);
        rs[gcol]  = s + part[tid] - cnt;
    }
}

__global__ __launch_bounds__(256) void k_edata(const uint2* __restrict__ bk,
                                               const int* __restrict__ bbase,
                                               const float* __restrict__ dis,
                                               const int* __restrict__ rs,
                                               int2* __restrict__ edata, int N) {
    __shared__ int cur[BKB];
    __shared__ float sdis[BKB];
    int b = blockIdx.x, tid = threadIdx.x;
    int gcol = b * BKB + tid;
    cur[tid]  = (gcol < N) ? rs[gcol] : 0;
    sdis[tid] = (gcol < N) ? dis[gcol] : 0.f;
    __syncthreads();
    int s = bbase[b], e = bbase[b + 1];
    for (int i = s + tid; i < e; i += 256) {
        uint2 q = bk[i];
        int c8 = (q.x >> 16) & 255;
        int r  = q.x & 0xFFFF;
        float nm = dis[r] * __uint_as_float(q.y) * sdis[c8];
        int pos = atomicAdd(&cur[c8], 1);
        edata[pos] = make_int2(r, __float_as_int(nm));
    }
}

// ------------------------------------------------- W convert+transpose: Wt[n][k] fp16
// Wt layout makes MFMA B-frags (n=lane&15, k=quad*8+j) contiguous 16B LDS reads.
__global__ __launch_bounds__(256) void k_wconv(const float* __restrict__ W,
                                               _Float16* __restrict__ Wt, int ncol) {
    int idx = blockIdx.x * 256 + threadIdx.x;
    if (idx < ncol * K128) {
        int n = idx % ncol, k = idx / ncol;
        Wt[n * K128 + k] = (_Float16)W[k * ncol + n];
    }
}

// ------------------------------------------------- MFMA fp16 GEMM, fp32 acc
// out[M,NCOL] = A[M,128] @ W[128,NCOL]. 256 thr = 4 waves x 16 rows.
// Whole K=128 staged once. LDS stride 136 halves: 16B-aligned b128 reads,
// bank offset 4/row -> 2-way aliasing (free, m136).
// v_mfma_f32_16x16x32_f16: A[m=lane&15][k=quad*8+j]; B via Wt[n][k];
// D: col=lane&15, row=quad*4+reg (m89-verified mapping, dtype-independent).
template <int NCOL, typename AT>
__global__ __launch_bounds__(256) void k_gemm(const AT* __restrict__ A,
                                              const _Float16* __restrict__ Wt,
                                              _Float16* __restrict__ out, int M) {
    constexpr int AS = 136;
    __shared__ _Float16 Ah[64 * AS];
    __shared__ _Float16 Wh[NCOL * AS];

    int tid  = threadIdx.x;
    int row0 = blockIdx.x * 64;

    // ---- stage A: 64 rows x 128 -> fp16 LDS
    if constexpr (std::is_same_v<AT, float>) {
#pragma unroll
        for (int q = 0; q < 8; q++) {              // 2048 float4 / 256 thr
            int idx = tid + 256 * q;
            int r = idx >> 5, c4 = (idx & 31) * 4;
            float4 v = ld4(A + (size_t)(row0 + r) * K128 + c4);
            sth4(&Ah[r * AS + c4], v);
        }
    } else {
#pragma unroll
        for (int q = 0; q < 4; q++) {              // 1024 x 8-half chunks
            int idx = tid + 256 * q;
            int r = idx >> 4, c8 = (idx & 15) * 8;
            *(half8*)&Ah[r * AS + c8] = *(const half8*)(A + (size_t)(row0 + r) * K128 + c8);
        }
    }
    // ---- stage Wt: NCOL x 128 fp16 (coalesced 16B)
#pragma unroll
    for (int q = 0; q < NCOL / 16; q++) {          // NCOL*16 chunks / 256 thr
        int idx = tid + 256 * q;
        int n = idx >> 4, c8 = (idx & 15) * 8;
        *(half8*)&Wh[n * AS + c8] = *(const half8*)(Wt + n * K128 + c8);
    }
    __syncthreads();

    int lane = tid & 63;
    int wv   = tid >> 6;        // wave: rows 16*wv..16*wv+15
    int m    = lane & 15;
    int quad = lane >> 4;

    f32x4 acc[NCOL / 16];
#pragma unroll
    for (int ct = 0; ct < NCOL / 16; ct++) acc[ct] = (f32x4){0.f, 0.f, 0.f, 0.f};

#pragma unroll
    for (int kt = 0; kt < 4; kt++) {
        half8 af = *(const half8*)&Ah[(wv * 16 + m) * AS + kt * 32 + quad * 8];
#pragma unroll
        for (int ct = 0; ct < NCOL / 16; ct++) {
            half8 bf = *(const half8*)&Wh[(ct * 16 + m) * AS + kt * 32 + quad * 8];
            acc[ct] = __builtin_amdgcn_mfma_f32_16x16x32_f16(af, bf, acc[ct], 0, 0, 0);
        }
    }

#pragma unroll
    for (int ct = 0; ct < NCOL / 16; ct++) {
#pragma unroll
        for (int r = 0; r < 4; r++) {
            int grow = row0 + wv * 16 + quad * 4 + r;
            out[(size_t)grow * NCOL + ct * 16 + m] = (_Float16)acc[ct][r];
        }
    }
}

// ------------------------------------------------- CSR gather agg, 4-way ILP
template <int F>
__global__ __launch_bounds__(256) void k_agg(const _Float16* __restrict__ xw,
                                             const float* __restrict__ dis,
                                             const int2* __restrict__ edata,
                                             const int* __restrict__ rs,
                                             const float* __restrict__ bias,
                                             _Float16* __restrict__ out, int N) {
    constexpr int TPN = F / 4;
    constexpr int NPB = 256 / TPN;
    int node = blockIdx.x * NPB + threadIdx.x / TPN;
    int j4   = (threadIdx.x % TPN) * 4;
    if (node >= N) return;
    float dv = dis[node];
    float sw = dv * dv;
    float4 self = ldh4(xw + (size_t)node * F + j4);
    float4 bv   = ld4(bias + j4);
    float4 a0, a1, a2, a3;
    a0.x = self.x * sw + bv.x;
    a0.y = self.y * sw + bv.y;
    a0.z = self.z * sw + bv.z;
    a0.w = self.w * sw + bv.w;
    a1 = make_float4(0.f, 0.f, 0.f, 0.f);
    a2 = a1; a3 = a1;
    int s = rs[node], e = rs[node + 1];
    int j = s;
    for (; j + 4 <= e; j += 4) {
        int2 q0 = edata[j + 0];
        int2 q1 = edata[j + 1];
        int2 q2 = edata[j + 2];
        int2 q3 = edata[j + 3];
        float4 v0 = ldh4(xw + (size_t)q0.x * F + j4);
        float4 v1 = ldh4(xw + (size_t)q1.x * F + j4);
        float4 v2 = ldh4(xw + (size_t)q2.x * F + j4);
        float4 v3 = ldh4(xw + (size_t)q3.x * F + j4);
        float n0 = __int_as_float(q0.y), n1 = __int_as_float(q1.y);
        float n2 = __int_as_float(q2.y), n3 = __int_as_float(q3.y);
        a0.x += n0 * v0.x; a0.y += n0 * v0.y; a0.z += n0 * v0.z; a0.w += n0 * v0.w;
        a1.x += n1 * v1.x; a1.y += n1 * v1.y; a1.z += n1 * v1.z; a1.w += n1 * v1.w;
        a2.x += n2 * v2.x; a2.y += n2 * v2.y; a2.z += n2 * v2.z; a2.w += n2 * v2.w;
        a3.x += n3 * v3.x; a3.y += n3 * v3.y; a3.z += n3 * v3.z; a3.w += n3 * v3.w;
    }
    for (; j < e; j++) {
        int2 q = edata[j];
        float nm = __int_as_float(q.y);
        float4 v = ldh4(xw + (size_t)q.x * F + j4);
        a0.x += nm * v.x; a0.y += nm * v.y; a0.z += nm * v.z; a0.w += nm * v.w;
    }
    float4 acc;
    acc.x = (a0.x + a1.x) + (a2.x + a3.x);
    acc.y = (a0.y + a1.y) + (a2.y + a3.y);
    acc.z = (a0.z + a1.z) + (a2.z + a3.z);
    acc.w = (a0.w + a1.w) + (a2.w + a3.w);
    acc.x = fmaxf(acc.x, 0.f); acc.y = fmaxf(acc.y, 0.f);
    acc.z = fmaxf(acc.z, 0.f); acc.w = fmaxf(acc.w, 0.f);
    sth4(out + (size_t)node * F + j4, acc);
}

// ------------------------------------------------- mean-pool accumulate (sorted batch)
#define POOL_NODES 256
__global__ __launch_bounds__(256) void k_pool(const _Float16* __restrict__ h,
                                              const int* __restrict__ batch,
                                              float* __restrict__ g, int* __restrict__ gcnt,
                                              int N) {
    int base  = blockIdx.x * POOL_NODES;
    int f     = threadIdx.x & 63;
    int slice = threadIdx.x >> 6;
    int lim   = base + POOL_NODES; if (lim > N) lim = N;
    float acc = 0.f;
    int cur = -1, cnt = 0;
    for (int i = base + slice; i < lim; i += 4) {
        int b = batch[i];
        if (b != cur) {
            if (cur >= 0) {
                atomicAdd(&g[cur * 64 + f], acc);
                if (f == 0) atomicAdd(&gcnt[cur], cnt);
            }
            cur = b; acc = 0.f; cnt = 0;
        }
        acc += (float)h[(size_t)i * 64 + f];
        cnt++;
    }
    if (cur >= 0) {
        atomicAdd(&g[cur * 64 + f], acc);
        if (f == 0) atomicAdd(&gcnt[cur], cnt);
    }
}

// ------------------------------------------------- FC: out[NG,FLAT] = (g/cnt) @ Wfc + bfc
__global__ __launch_bounds__(256) void k_fc(const float* __restrict__ g,
                                            const int* __restrict__ gcnt,
                                            const float* __restrict__ Wfc,
                                            const float* __restrict__ bfc,
                                            float* __restrict__ out) {
    __shared__ float gs[64];
    int i = blockIdx.y;
    int j = blockIdx.x * blockDim.x + threadIdx.x;
    if (threadIdx.x < 64) {
        float c = (float)gcnt[i];
        gs[threadIdx.x] = g[i * 64 + threadIdx.x] / fmaxf(c, 1.0f);
    }
    __syncthreads();
    if (j >= FLAT) return;
    float acc = bfc[j];
#pragma unroll 8
    for (int k = 0; k < 64; k++) acc += gs[k] * Wfc[k * FLAT + j];
    out[(size_t)i * FLAT + j] = acc;
}

// ================================================================ launcher
extern "C" void kernel_launch(void* const* d_in, const int* in_sizes, int n_in,
                              void* d_out, int out_size, void* d_ws, size_t ws_size,
                              hipStream_t stream) {
    const float* x    = (const float*)d_in[0];
    const int*   ei   = (const int*)d_in[1];
    const float* ew   = (const float*)d_in[2];
    const int*   batch= (const int*)d_in[3];
    const float* W1   = (const float*)d_in[4];
    const float* b1   = (const float*)d_in[5];
    const float* W2   = (const float*)d_in[6];
    const float* b2   = (const float*)d_in[7];
    const float* Wfc  = (const float*)d_in[8];
    const float* bfc  = (const float*)d_in[9];
    float* out = (float*)d_out;

    const int N = in_sizes[0] / K128;   // 40000
    const int E = in_sizes[2];          // 640000
    const int* row = ei;
    const int* col = ei + E;
    const int nbk = (N + BKB - 1) / BKB;   // 157 buckets
    const int neb = (E + 1023) / 1024;     // edge-chunk blocks

    // ---- workspace carve (256B aligned)
    char* p = (char*)d_ws;
    auto alloc = [&](size_t bytes) -> void* {
        void* r = (void*)p;
        p += (bytes + 255) & ~(size_t)255;
        return r;
    };
    float*     dis   = (float*)    alloc((size_t)N * 4);
    int*       rs    = (int*)      alloc((size_t)(N + 1) * 4);
    uint2*     bk    = (uint2*)    alloc((size_t)E * 8);
    int2*      edata = (int2*)     alloc((size_t)E * 8);
    _Float16*  xw1   = (_Float16*) alloc((size_t)N * 128 * 2);
    _Float16*  h1    = (_Float16*) alloc((size_t)N * 128 * 2);
    _Float16*  xw2   = (_Float16*) alloc((size_t)N * 64 * 2);
    _Float16*  h2    = (_Float16*) alloc((size_t)N * 64 * 2);
    _Float16*  Wt1   = (_Float16*) alloc((size_t)128 * 128 * 2);
    _Float16*  Wt2   = (_Float16*) alloc((size_t)64 * 128 * 2);
    float*     g     = (float*)    alloc(64 * 64 * 4);
    int*       gcnt  = (int*)      alloc(64 * 4);
    int*       bhist = (int*)      alloc(BKB * 4);
    int*       bbase = (int*)      alloc((BKB + 2) * 4);
    int*       bcur  = (int*)      alloc(BKB * 4);

    // ---- zero accumulators (ws is poisoned 0xAA before every launch)
    hipMemsetAsync(bhist, 0, BKB * 4,     stream);
    hipMemsetAsync(g,     0, 64 * 64 * 4, stream);
    hipMemsetAsync(gcnt,  0, 64 * 4,      stream);

    // ---- CSR build (bucket counting sort, shared by both layers)
    k_bhist <<<neb, 256, 0, stream>>>(col, bhist, E, nbk);
    k_bscan <<<1,   256, 0, stream>>>(bhist, bbase, bcur, rs + N, E, nbk);
    k_bucket<<<neb, 256, 0, stream>>>(row, col, ew, bcur, bk, E, nbk);
    k_cols  <<<nbk, 256, 0, stream>>>(bk, bbase, dis, rs, N);
    k_edata <<<nbk, 256, 0, stream>>>(bk, bbase, dis, rs, edata, N);

    // ---- weight convert+transpose (fp16)
    k_wconv<<<(128 * 128 + 255) / 256, 256, 0, stream>>>(W1, Wt1, 128);
    k_wconv<<<(64 * 128 + 255) / 256, 256, 0, stream>>>(W2, Wt2, 64);

    // ---- layer 1 (MFMA fp16 GEMM: 64 rows/block, N=40000 = 625*64 exact)
    k_gemm<128, float><<<N / 64, 256, 0, stream>>>(x, Wt1, xw1, N);
    k_agg<128><<<(N + 7) / 8, 256, 0, stream>>>(xw1, dis, edata, rs, b1, h1, N);

    // ---- layer 2
    k_gemm<64, _Float16><<<N / 64, 256, 0, stream>>>(h1, Wt2, xw2, N);
    k_agg<64><<<(N + 15) / 16, 256, 0, stream>>>(xw2, dis, edata, rs, b2, h2, N);

    // ---- pool + fc
    k_pool<<<(N + POOL_NODES - 1) / POOL_NODES, 256, 0, stream>>>(h2, batch, g, gcnt, N);
    dim3 fcg((FLAT + 255) / 256, NG);
    k_fc<<<fcg, 256, 0, stream>>>(g, gcnt, Wfc, bfc, out);
}

// Round 10
// 203.595 us; speedup vs baseline: 4.0150x; 1.1194x over previous
//
#include <hip/hip_runtime.h>
#include <hip/hip_bf16.h>
#include <hip/hip_fp16.h>
#include <type_traits>

#define NG 64          // number of graphs
#define FLAT 2904      // FC output width
#define K128 128       // inner dim for both GEMMs
#define BKB 256        // cols per bucket (col >> 8)

typedef _Float16 h4 __attribute__((ext_vector_type(4)));     // 8B
typedef _Float16 half8 __attribute__((ext_vector_type(8)));  // 16B MFMA frag
typedef float f32x4 __attribute__((ext_vector_type(4)));

// ---------------------------------------------------------------- utilities
__device__ __forceinline__ float4 ld4(const float* p) { return *(const float4*)p; }
__device__ __forceinline__ void st4(float* p, float4 v) { *(float4*)p = v; }
__device__ __forceinline__ float4 ldh4(const _Float16* p) {
    h4 h = *(const h4*)p;
    return make_float4((float)h.x, (float)h.y, (float)h.z, (float)h.w);
}
__device__ __forceinline__ void sth4(_Float16* p, float4 v) {
    h4 h; h.x = (_Float16)v.x; h.y = (_Float16)v.y; h.z = (_Float16)v.z; h.w = (_Float16)v.w;
    *(h4*)p = h;
}

// ------------------------------------------------- zero all accumulators (1 dispatch)
__global__ __launch_bounds__(256) void k_zero(int* __restrict__ bhist,
                                              float* __restrict__ g,
                                              int* __restrict__ gcnt) {
    int tid = threadIdx.x;
    for (int i = tid; i < BKB; i += 256) bhist[i] = 0;
    for (int i = tid; i < NG * 64; i += 256) g[i] = 0.f;
    if (tid < NG) gcnt[tid] = 0;
}

// ================================================================ CSR build
// bucket counting sort (R7) + algebraic refactor (R10): edata stores
// (row, w'=ew*dis[col]); xw rows are pre-scaled by dis in the GEMM epilogue,
// so agg computes sum w'*xw'[row] + dis[node]*xw'[node] + b == reference.

__global__ __launch_bounds__(256) void k_bhist(const int* __restrict__ col,
                                               int* __restrict__ bhist, int E, int nbk) {
    __shared__ int h[BKB];
    int tid = threadIdx.x;
    for (int i = tid; i < nbk; i += 256) h[i] = 0;
    __syncthreads();
    int base = blockIdx.x * 1024 + tid * 4;
#pragma unroll
    for (int q = 0; q < 4; q++) {
        int e = base + q;
        if (e < E) atomicAdd(&h[col[e] >> 8], 1);
    }
    __syncthreads();
    for (int i = tid; i < nbk; i += 256) if (h[i]) atomicAdd(&bhist[i], h[i]);
}

__global__ __launch_bounds__(256) void k_bscan(const int* __restrict__ bhist,
                                               int* __restrict__ bbase,
                                               int* __restrict__ bcursor,
                                               int* __restrict__ rsN, int E, int nbk) {
    __shared__ int part[256];
    int tid = threadIdx.x;
    int v = (tid < nbk) ? bhist[tid] : 0;
    part[tid] = v;
    __syncthreads();
    for (int off = 1; off < 256; off <<= 1) {
        int t = (tid >= off) ? part[tid - off] : 0;
        __syncthreads();
        part[tid] += t;
        __syncthreads();
    }
    if (tid < nbk) { int ex = part[tid] - v; bbase[tid] = ex; bcursor[tid] = ex; }
    if (tid == nbk - 1) bbase[nbk] = part[tid];
    if (tid == 0) *rsN = E;
}

__global__ __launch_bounds__(256) void k_bucket(const int* __restrict__ row,
                                                const int* __restrict__ col,
                                                const float* __restrict__ ew,
                                                int* __restrict__ bcursor,
                                                uint2* __restrict__ bk, int E, int nbk) {
    __shared__ int h[BKB];
    __shared__ int cur[BKB];
    int tid = threadIdx.x;
    for (int i = tid; i < nbk; i += 256) h[i] = 0;
    __syncthreads();
    int base = blockIdx.x * 1024 + tid * 4;
    int c[4];
#pragma unroll
    for (int q = 0; q < 4; q++) {
        int e = base + q;
        c[q] = (e < E) ? col[e] : -1;
        if (c[q] >= 0) atomicAdd(&h[c[q] >> 8], 1);
    }
    __syncthreads();
    for (int i = tid; i < nbk; i += 256) cur[i] = h[i] ? atomicAdd(&bcursor[i], h[i]) : 0;
    __syncthreads();
#pragma unroll
    for (int q = 0; q < 4; q++) {
        int e = base + q;
        if (c[q] >= 0) {
            int slot = atomicAdd(&cur[c[q] >> 8], 1);
            bk[slot] = make_uint2(((unsigned)c[q] << 16) | (unsigned)row[e],
                                  __float_as_uint(ew[e]));
        }
    }
}

// ---- fused: per-bucket degree/count -> dis/rs, then edge placement with
// w' = ew*dis[col] (bucket-local dis only — the refactor makes this legal).
__global__ __launch_bounds__(256) void k_colsedata(const uint2* __restrict__ bk,
                                                   const int* __restrict__ bbase,
                                                   float* __restrict__ dis,
                                                   int* __restrict__ rs,
                                                   int2* __restrict__ edata, int N) {
    __shared__ float sdeg[BKB];
    __shared__ int scnt[BKB];
    __shared__ int part[BKB];
    __shared__ int cur[BKB];
    __shared__ float sdis[BKB];
    int b = blockIdx.x, tid = threadIdx.x;
    sdeg[tid] = 0.f; scnt[tid] = 0;
    __syncthreads();
    int s = bbase[b], e = bbase[b + 1];
    for (int i = s + tid; i < e; i += 256) {
        uint2 q = bk[i];
        int c8 = (q.x >> 16) & 255;
        atomicAdd(&sdeg[c8], __uint_as_float(q.y));
        atomicAdd(&scnt[c8], 1);
    }
    __syncthreads();
    int cnt = scnt[tid];
    part[tid] = cnt;
    __syncthreads();
    for (int off = 1; off < 256; off <<= 1) {
        int t = (tid >= off) ? part[tid - off] : 0;
        __syncthreads();
        part[tid] += t;
        __syncthreads();
    }
    float d  = rsqrtf(sdeg[tid] + 1.0f);
    int   r0 = s + part[tid] - cnt;
    int gcol = b * BKB + tid;
    if (gcol < N) { dis[gcol] = d; rs[gcol] = r0; }
    cur[tid] = r0; sdis[tid] = d;
    __syncthreads();
    for (int i = s + tid; i < e; i += 256) {
        uint2 q = bk[i];
        int c8 = (q.x >> 16) & 255;
        int r  = q.x & 0xFFFF;
        float w = __uint_as_float(q.y) * sdis[c8];   // ew * dis[col]
        int pos = atomicAdd(&cur[c8], 1);
        edata[pos] = make_int2(r, __float_as_int(w));
    }
}

// ------------------------------------------------- both W converts, 1 dispatch
__global__ __launch_bounds__(256) void k_wconv2(const float* __restrict__ W1,
                                                const float* __restrict__ W2,
                                                _Float16* __restrict__ Wt1,
                                                _Float16* __restrict__ Wt2) {
    int idx = blockIdx.x * 256 + threadIdx.x;
    if (idx < 128 * 128) {
        int n = idx % 128, k = idx / 128;
        Wt1[n * K128 + k] = (_Float16)W1[k * 128 + n];
    } else {
        int i = idx - 128 * 128;
        if (i < 64 * 128) {
            int n = i % 64, k = i / 64;
            Wt2[n * K128 + k] = (_Float16)W2[k * 64 + n];
        }
    }
}

// ------------------------------------------------- MFMA fp16 GEMM, dis-scaled epilogue
// out[r] = dis[r] * (A[r] @ W)  stored fp16 (the xw' refactor).
template <int NCOL, typename AT>
__global__ __launch_bounds__(256) void k_gemm(const AT* __restrict__ A,
                                              const _Float16* __restrict__ Wt,
                                              const float* __restrict__ dis,
                                              _Float16* __restrict__ out, int M) {
    constexpr int AS = 136;
    __shared__ _Float16 Ah[64 * AS];
    __shared__ _Float16 Wh[NCOL * AS];

    int tid  = threadIdx.x;
    int row0 = blockIdx.x * 64;

    if constexpr (std::is_same_v<AT, float>) {
#pragma unroll
        for (int q = 0; q < 8; q++) {
            int idx = tid + 256 * q;
            int r = idx >> 5, c4 = (idx & 31) * 4;
            float4 v = ld4(A + (size_t)(row0 + r) * K128 + c4);
            sth4(&Ah[r * AS + c4], v);
        }
    } else {
#pragma unroll
        for (int q = 0; q < 4; q++) {
            int idx = tid + 256 * q;
            int r = idx >> 4, c8 = (idx & 15) * 8;
            *(half8*)&Ah[r * AS + c8] = *(const half8*)(A + (size_t)(row0 + r) * K128 + c8);
        }
    }
#pragma unroll
    for (int q = 0; q < NCOL / 16; q++) {
        int idx = tid + 256 * q;
        int n = idx >> 4, c8 = (idx & 15) * 8;
        *(half8*)&Wh[n * AS + c8] = *(const half8*)(Wt + n * K128 + c8);
    }
    __syncthreads();

    int lane = tid & 63;
    int wv   = tid >> 6;
    int m    = lane & 15;
    int quad = lane >> 4;

    f32x4 acc[NCOL / 16];
#pragma unroll
    for (int ct = 0; ct < NCOL / 16; ct++) acc[ct] = (f32x4){0.f, 0.f, 0.f, 0.f};

#pragma unroll
    for (int kt = 0; kt < 4; kt++) {
        half8 af = *(const half8*)&Ah[(wv * 16 + m) * AS + kt * 32 + quad * 8];
#pragma unroll
        for (int ct = 0; ct < NCOL / 16; ct++) {
            half8 bf = *(const half8*)&Wh[(ct * 16 + m) * AS + kt * 32 + quad * 8];
            acc[ct] = __builtin_amdgcn_mfma_f32_16x16x32_f16(af, bf, acc[ct], 0, 0, 0);
        }
    }

    float d[4];
#pragma unroll
    for (int r = 0; r < 4; r++) d[r] = dis[row0 + wv * 16 + quad * 4 + r];
#pragma unroll
    for (int ct = 0; ct < NCOL / 16; ct++) {
#pragma unroll
        for (int r = 0; r < 4; r++) {
            int grow = row0 + wv * 16 + quad * 4 + r;
            out[(size_t)grow * NCOL + ct * 16 + m] = (_Float16)(acc[ct][r] * d[r]);
        }
    }
}

// ------------------------------------------------- agg F=128, 8-way ILP
// h = relu( sum w'*xw'[row] + dis[node]*xw'[node] + b )
__global__ __launch_bounds__(256) void k_agg128(const _Float16* __restrict__ xw,
                                                const float* __restrict__ dis,
                                                const int2* __restrict__ edata,
                                                const int* __restrict__ rs,
                                                const float* __restrict__ bias,
                                                _Float16* __restrict__ out, int N) {
    constexpr int F = 128;
    int node = blockIdx.x * 8 + (threadIdx.x >> 5);
    int j4   = (threadIdx.x & 31) * 4;
    float dv = dis[node];
    float4 self = ldh4(xw + (size_t)node * F + j4);
    float4 bv   = ld4(bias + j4);
    float4 a0 = make_float4(self.x * dv + bv.x, self.y * dv + bv.y,
                            self.z * dv + bv.z, self.w * dv + bv.w);
    float4 a1 = make_float4(0.f, 0.f, 0.f, 0.f);
    float4 a2 = a1, a3 = a1, a4 = a1, a5 = a1, a6 = a1, a7 = a1;
    int s = rs[node], e = rs[node + 1];
    int j = s;
    for (; j + 8 <= e; j += 8) {
        int2 q0 = edata[j + 0], q1 = edata[j + 1], q2 = edata[j + 2], q3 = edata[j + 3];
        int2 q4 = edata[j + 4], q5 = edata[j + 5], q6 = edata[j + 6], q7 = edata[j + 7];
        float4 v0 = ldh4(xw + (size_t)q0.x * F + j4);
        float4 v1 = ldh4(xw + (size_t)q1.x * F + j4);
        float4 v2 = ldh4(xw + (size_t)q2.x * F + j4);
        float4 v3 = ldh4(xw + (size_t)q3.x * F + j4);
        float4 v4 = ldh4(xw + (size_t)q4.x * F + j4);
        float4 v5 = ldh4(xw + (size_t)q5.x * F + j4);
        float4 v6 = ldh4(xw + (size_t)q6.x * F + j4);
        float4 v7 = ldh4(xw + (size_t)q7.x * F + j4);
        float n0 = __int_as_float(q0.y), n1 = __int_as_float(q1.y);
        float n2 = __int_as_float(q2.y), n3 = __int_as_float(q3.y);
        float n4 = __int_as_float(q4.y), n5 = __int_as_float(q5.y);
        float n6 = __int_as_float(q6.y), n7 = __int_as_float(q7.y);
        a0.x += n0 * v0.x; a0.y += n0 * v0.y; a0.z += n0 * v0.z; a0.w += n0 * v0.w;
        a1.x += n1 * v1.x; a1.y += n1 * v1.y; a1.z += n1 * v1.z; a1.w += n1 * v1.w;
        a2.x += n2 * v2.x; a2.y += n2 * v2.y; a2.z += n2 * v2.z; a2.w += n2 * v2.w;
        a3.x += n3 * v3.x; a3.y += n3 * v3.y; a3.z += n3 * v3.z; a3.w += n3 * v3.w;
        a4.x += n4 * v4.x; a4.y += n4 * v4.y; a4.z += n4 * v4.z; a4.w += n4 * v4.w;
        a5.x += n5 * v5.x; a5.y += n5 * v5.y; a5.z += n5 * v5.z; a5.w += n5 * v5.w;
        a6.x += n6 * v6.x; a6.y += n6 * v6.y; a6.z += n6 * v6.z; a6.w += n6 * v6.w;
        a7.x += n7 * v7.x; a7.y += n7 * v7.y; a7.z += n7 * v7.z; a7.w += n7 * v7.w;
    }
    for (; j + 4 <= e; j += 4) {
        int2 q0 = edata[j + 0], q1 = edata[j + 1], q2 = edata[j + 2], q3 = edata[j + 3];
        float4 v0 = ldh4(xw + (size_t)q0.x * F + j4);
        float4 v1 = ldh4(xw + (size_t)q1.x * F + j4);
        float4 v2 = ldh4(xw + (size_t)q2.x * F + j4);
        float4 v3 = ldh4(xw + (size_t)q3.x * F + j4);
        float n0 = __int_as_float(q0.y), n1 = __int_as_float(q1.y);
        float n2 = __int_as_float(q2.y), n3 = __int_as_float(q3.y);
        a0.x += n0 * v0.x; a0.y += n0 * v0.y; a0.z += n0 * v0.z; a0.w += n0 * v0.w;
        a1.x += n1 * v1.x; a1.y += n1 * v1.y; a1.z += n1 * v1.z; a1.w += n1 * v1.w;
        a2.x += n2 * v2.x; a2.y += n2 * v2.y; a2.z += n2 * v2.z; a2.w += n2 * v2.w;
        a3.x += n3 * v3.x; a3.y += n3 * v3.y; a3.z += n3 * v3.z; a3.w += n3 * v3.w;
    }
    for (; j < e; j++) {
        int2 q = edata[j];
        float nm = __int_as_float(q.y);
        float4 v = ldh4(xw + (size_t)q.x * F + j4);
        a0.x += nm * v.x; a0.y += nm * v.y; a0.z += nm * v.z; a0.w += nm * v.w;
    }
    float4 acc;
    acc.x = ((a0.x + a1.x) + (a2.x + a3.x)) + ((a4.x + a5.x) + (a6.x + a7.x));
    acc.y = ((a0.y + a1.y) + (a2.y + a3.y)) + ((a4.y + a5.y) + (a6.y + a7.y));
    acc.z = ((a0.z + a1.z) + (a2.z + a3.z)) + ((a4.z + a5.z) + (a6.z + a7.z));
    acc.w = ((a0.w + a1.w) + (a2.w + a3.w)) + ((a4.w + a5.w) + (a6.w + a7.w));
    acc.x = fmaxf(acc.x, 0.f); acc.y = fmaxf(acc.y, 0.f);
    acc.z = fmaxf(acc.z, 0.f); acc.w = fmaxf(acc.w, 0.f);
    sth4(out + (size_t)node * F + j4, acc);
}

// ------------------------------------------------- agg F=64 fused with mean-pool
// h2 never materialized: block (16 nodes) reduces into g via sorted-segment
// flush (<= ~2 graphs/block -> ~64-128 atomics/block).
__global__ __launch_bounds__(256) void k_agg_pool(const _Float16* __restrict__ xw,
                                                  const float* __restrict__ dis,
                                                  const int2* __restrict__ edata,
                                                  const int* __restrict__ rs,
                                                  const float* __restrict__ bias,
                                                  const int* __restrict__ batch,
                                                  float* __restrict__ g,
                                                  int* __restrict__ gcnt, int N) {
    constexpr int F = 64;
    __shared__ float T[16][F + 4];
    __shared__ int sb[16];
    int tid  = threadIdx.x;
    int base = blockIdx.x * 16;
    int nl   = tid >> 4;            // local node 0..15
    int node = base + nl;
    int j4   = (tid & 15) * 4;
    if (tid < 16) sb[tid] = batch[base + tid];

    float dv = dis[node];
    float4 self = ldh4(xw + (size_t)node * F + j4);
    float4 bv   = ld4(bias + j4);
    float4 a0 = make_float4(self.x * dv + bv.x, self.y * dv + bv.y,
                            self.z * dv + bv.z, self.w * dv + bv.w);
    float4 a1 = make_float4(0.f, 0.f, 0.f, 0.f);
    float4 a2 = a1, a3 = a1;
    int s = rs[node], e = rs[node + 1];
    int j = s;
    for (; j + 4 <= e; j += 4) {
        int2 q0 = edata[j + 0], q1 = edata[j + 1], q2 = edata[j + 2], q3 = edata[j + 3];
        float4 v0 = ldh4(xw + (size_t)q0.x * F + j4);
        float4 v1 = ldh4(xw + (size_t)q1.x * F + j4);
        float4 v2 = ldh4(xw + (size_t)q2.x * F + j4);
        float4 v3 = ldh4(xw + (size_t)q3.x * F + j4);
        float n0 = __int_as_float(q0.y), n1 = __int_as_float(q1.y);
        float n2 = __int_as_float(q2.y), n3 = __int_as_float(q3.y);
        a0.x += n0 * v0.x; a0.y += n0 * v0.y; a0.z += n0 * v0.z; a0.w += n0 * v0.w;
        a1.x += n1 * v1.x; a1.y += n1 * v1.y; a1.z += n1 * v1.z; a1.w += n1 * v1.w;
        a2.x += n2 * v2.x; a2.y += n2 * v2.y; a2.z += n2 * v2.z; a2.w += n2 * v2.w;
        a3.x += n3 * v3.x; a3.y += n3 * v3.y; a3.z += n3 * v3.z; a3.w += n3 * v3.w;
    }
    for (; j < e; j++) {
        int2 q = edata[j];
        float nm = __int_as_float(q.y);
        float4 v = ldh4(xw + (size_t)q.x * F + j4);
        a0.x += nm * v.x; a0.y += nm * v.y; a0.z += nm * v.z; a0.w += nm * v.w;
    }
    float4 acc;
    acc.x = (a0.x + a1.x) + (a2.x + a3.x);
    acc.y = (a0.y + a1.y) + (a2.y + a3.y);
    acc.z = (a0.z + a1.z) + (a2.z + a3.z);
    acc.w = (a0.w + a1.w) + (a2.w + a3.w);
    T[nl][j4 + 0] = fmaxf(acc.x, 0.f);
    T[nl][j4 + 1] = fmaxf(acc.y, 0.f);
    T[nl][j4 + 2] = fmaxf(acc.z, 0.f);
    T[nl][j4 + 3] = fmaxf(acc.w, 0.f);
    __syncthreads();
    if (tid < 64) {
        int f = tid;
        float run = 0.f;
        int cur = -1, cnt = 0;
        for (int k = 0; k < 16; k++) {
            int b = sb[k];
            if (b != cur) {
                if (cur >= 0) {
                    atomicAdd(&g[cur * 64 + f], run);
                    if (f == 0) atomicAdd(&gcnt[cur], cnt);
                }
                cur = b; run = 0.f; cnt = 0;
            }
            run += T[k][f];
            cnt++;
        }
        atomicAdd(&g[cur * 64 + f], run);
        if (f == 0) atomicAdd(&gcnt[cur], cnt);
    }
}

// ------------------------------------------------- FC: out[NG,FLAT] = (g/cnt) @ Wfc + bfc
__global__ __launch_bounds__(256) void k_fc(const float* __restrict__ g,
                                            const int* __restrict__ gcnt,
                                            const float* __restrict__ Wfc,
                                            const float* __restrict__ bfc,
                                            float* __restrict__ out) {
    __shared__ float gs[64];
    int i = blockIdx.y;
    int j = blockIdx.x * blockDim.x + threadIdx.x;
    if (threadIdx.x < 64) {
        float c = (float)gcnt[i];
        gs[threadIdx.x] = g[i * 64 + threadIdx.x] / fmaxf(c, 1.0f);
    }
    __syncthreads();
    if (j >= FLAT) return;
    float acc = bfc[j];
#pragma unroll 8
    for (int k = 0; k < 64; k++) acc += gs[k] * Wfc[k * FLAT + j];
    out[(size_t)i * FLAT + j] = acc;
}

// ================================================================ launcher
extern "C" void kernel_launch(void* const* d_in, const int* in_sizes, int n_in,
                              void* d_out, int out_size, void* d_ws, size_t ws_size,
                              hipStream_t stream) {
    const float* x    = (const float*)d_in[0];
    const int*   ei   = (const int*)d_in[1];
    const float* ew   = (const float*)d_in[2];
    const int*   batch= (const int*)d_in[3];
    const float* W1   = (const float*)d_in[4];
    const float* b1   = (const float*)d_in[5];
    const float* W2   = (const float*)d_in[6];
    const float* b2   = (const float*)d_in[7];
    const float* Wfc  = (const float*)d_in[8];
    const float* bfc  = (const float*)d_in[9];
    float* out = (float*)d_out;

    const int N = in_sizes[0] / K128;   // 40000
    const int E = in_sizes[2];          // 640000
    const int* row = ei;
    const int* col = ei + E;
    const int nbk = (N + BKB - 1) / BKB;   // 157 buckets
    const int neb = (E + 1023) / 1024;     // edge-chunk blocks

    // ---- workspace carve (256B aligned)
    char* p = (char*)d_ws;
    auto alloc = [&](size_t bytes) -> void* {
        void* r = (void*)p;
        p += (bytes + 255) & ~(size_t)255;
        return r;
    };
    float*     dis   = (float*)    alloc((size_t)N * 4);
    int*       rs    = (int*)      alloc((size_t)(N + 1) * 4);
    uint2*     bk    = (uint2*)    alloc((size_t)E * 8);
    int2*      edata = (int2*)     alloc((size_t)E * 8);
    _Float16*  xw1   = (_Float16*) alloc((size_t)N * 128 * 2);
    _Float16*  h1    = (_Float16*) alloc((size_t)N * 128 * 2);
    _Float16*  xw2   = (_Float16*) alloc((size_t)N * 64 * 2);
    _Float16*  Wt1   = (_Float16*) alloc((size_t)128 * 128 * 2);
    _Float16*  Wt2   = (_Float16*) alloc((size_t)64 * 128 * 2);
    float*     g     = (float*)    alloc(64 * 64 * 4);
    int*       gcnt  = (int*)      alloc(64 * 4);
    int*       bhist = (int*)      alloc(BKB * 4);
    int*       bbase = (int*)      alloc((BKB + 2) * 4);
    int*       bcur  = (int*)      alloc(BKB * 4);

    // ---- CSR build (bucket counting sort, shared by both layers)
    k_zero     <<<1,   256, 0, stream>>>(bhist, g, gcnt);
    k_bhist    <<<neb, 256, 0, stream>>>(col, bhist, E, nbk);
    k_bscan    <<<1,   256, 0, stream>>>(bhist, bbase, bcur, rs + N, E, nbk);
    k_bucket   <<<neb, 256, 0, stream>>>(row, col, ew, bcur, bk, E, nbk);
    k_colsedata<<<nbk, 256, 0, stream>>>(bk, bbase, dis, rs, edata, N);
    k_wconv2   <<<(192 * 128 + 255) / 256, 256, 0, stream>>>(W1, W2, Wt1, Wt2);

    // ---- layer 1 (N = 40000 = 625*64 exact)
    k_gemm<128, float><<<N / 64, 256, 0, stream>>>(x, Wt1, dis, xw1, N);
    k_agg128<<<N / 8, 256, 0, stream>>>(xw1, dis, edata, rs, b1, h1, N);

    // ---- layer 2 + fused pool
    k_gemm<64, _Float16><<<N / 64, 256, 0, stream>>>(h1, Wt2, dis, xw2, N);
    k_agg_pool<<<N / 16, 256, 0, stream>>>(xw2, dis, edata, rs, b2, batch, g, gcnt, N);

    // ---- fc
    dim3 fcg((FLAT + 255) / 256, NG);
    k_fc<<<fcg, 256, 0, stream>>>(g, gcnt, Wfc, bfc, out);
}

// Round 11
// 193.742 us; speedup vs baseline: 4.2192x; 1.0509x over previous
//
#include <hip/hip_runtime.h>
#include <hip/hip_bf16.h>
#include <hip/hip_fp16.h>
#include <type_traits>

#define NG 64          // number of graphs
#define FLAT 2904      // FC output width
#define K128 128       // inner dim for both GEMMs
#define BKB 256        // cols per bucket (col >> 8)

typedef _Float16 h4 __attribute__((ext_vector_type(4)));     // 8B
typedef _Float16 half8 __attribute__((ext_vector_type(8)));  // 16B MFMA frag
typedef float f32x4 __attribute__((ext_vector_type(4)));

// ---------------------------------------------------------------- utilities
__device__ __forceinline__ float4 ld4(const float* p) { return *(const float4*)p; }
__device__ __forceinline__ float4 ldh4(const _Float16* p) {
    h4 h = *(const h4*)p;
    return make_float4((float)h.x, (float)h.y, (float)h.z, (float)h.w);
}
__device__ __forceinline__ void sth4(_Float16* p, float4 v) {
    h4 h; h.x = (_Float16)v.x; h.y = (_Float16)v.y; h.z = (_Float16)v.z; h.w = (_Float16)v.w;
    *(h4*)p = h;
}
__device__ __forceinline__ float unpack_w(unsigned q) {
    return (float)__builtin_bit_cast(_Float16, (unsigned short)(q & 0xFFFFu));
}

// ------------------------------------------------- init: zero accum + both W converts
// block 0 zeroes bhist/bcursor/g/gcnt; all 96 blocks share the wconv work.
__global__ __launch_bounds__(256) void k_init(int* __restrict__ bhist,
                                              int* __restrict__ bcursor,
                                              float* __restrict__ g,
                                              int* __restrict__ gcnt,
                                              const float* __restrict__ W1,
                                              const float* __restrict__ W2,
                                              _Float16* __restrict__ Wt1,
                                              _Float16* __restrict__ Wt2) {
    int tid = threadIdx.x;
    if (blockIdx.x == 0) {
        bhist[tid] = 0; bcursor[tid] = 0;
        for (int i = tid; i < NG * 64; i += 256) g[i] = 0.f;
        if (tid < NG) gcnt[tid] = 0;
    }
    int idx = blockIdx.x * 256 + tid;
    if (idx < 128 * 128) {
        int n = idx % 128, k = idx / 128;
        Wt1[n * K128 + k] = (_Float16)W1[k * 128 + n];
    } else if (idx < 128 * 128 + 64 * 128) {
        int i = idx - 128 * 128;
        int n = i % 64, k = i / 64;
        Wt2[n * K128 + k] = (_Float16)W2[k * 64 + n];
    }
}

// ================================================================ CSR build
// bucket counting sort; per-block redundant 157-entry scan of bhist replaces
// the k_bscan dispatch. edata = (row<<16)|fp16(w'), w' = ew*dis[col].

__global__ __launch_bounds__(256) void k_bhist(const int* __restrict__ col,
                                               int* __restrict__ bhist, int E, int nbk) {
    __shared__ int h[BKB];
    int tid = threadIdx.x;
    for (int i = tid; i < nbk; i += 256) h[i] = 0;
    __syncthreads();
    int base = blockIdx.x * 1024 + tid * 4;
#pragma unroll
    for (int q = 0; q < 4; q++) {
        int e = base + q;
        if (e < E) atomicAdd(&h[col[e] >> 8], 1);
    }
    __syncthreads();
    for (int i = tid; i < nbk; i += 256) if (h[i]) atomicAdd(&bhist[i], h[i]);
}

__global__ __launch_bounds__(256) void k_bucket(const int* __restrict__ row,
                                                const int* __restrict__ col,
                                                const float* __restrict__ ew,
                                                const int* __restrict__ bhist,
                                                int* __restrict__ bcursor,
                                                uint2* __restrict__ bk, int E, int nbk) {
    __shared__ int part[256];
    __shared__ int h[BKB];
    __shared__ int cur[BKB];
    int tid = threadIdx.x;
    int gh = (tid < nbk) ? bhist[tid] : 0;
    part[tid] = gh;
    h[tid] = 0;
    __syncthreads();
    for (int off = 1; off < 256; off <<= 1) {
        int t = (tid >= off) ? part[tid - off] : 0;
        __syncthreads();
        part[tid] += t;
        __syncthreads();
    }
    int ex = part[tid] - gh;                  // exclusive global bucket base
    int base = blockIdx.x * 1024 + tid * 4;
    int c[4];
#pragma unroll
    for (int q = 0; q < 4; q++) {
        int e = base + q;
        c[q] = (e < E) ? col[e] : -1;
        if (c[q] >= 0) atomicAdd(&h[c[q] >> 8], 1);
    }
    __syncthreads();
    if (tid < nbk) cur[tid] = h[tid] ? ex + atomicAdd(&bcursor[tid], h[tid]) : 0;
    __syncthreads();
#pragma unroll
    for (int q = 0; q < 4; q++) {
        int e = base + q;
        if (c[q] >= 0) {
            int slot = atomicAdd(&cur[c[q] >> 8], 1);
            bk[slot] = make_uint2(((unsigned)c[q] << 16) | (unsigned)row[e],
                                  __float_as_uint(ew[e]));
        }
    }
}

// ---- fused: bucket base (local scan) -> degree/count -> dis/rs -> edata
__global__ __launch_bounds__(256) void k_colsedata(const uint2* __restrict__ bk,
                                                   const int* __restrict__ bhist,
                                                   float* __restrict__ dis,
                                                   int* __restrict__ rs,
                                                   unsigned* __restrict__ edata,
                                                   int N, int E, int nbk) {
    __shared__ int part[256];
    __shared__ float sdeg[BKB];
    __shared__ int scnt[BKB];
    __shared__ int cur[BKB];
    __shared__ float sdis[BKB];
    __shared__ int sse[2];
    int b = blockIdx.x, tid = threadIdx.x;
    int gh = (tid < nbk) ? bhist[tid] : 0;
    part[tid] = gh;
    sdeg[tid] = 0.f; scnt[tid] = 0;
    __syncthreads();
    for (int off = 1; off < 256; off <<= 1) {
        int t = (tid >= off) ? part[tid - off] : 0;
        __syncthreads();
        part[tid] += t;
        __syncthreads();
    }
    if (tid == b) { sse[0] = part[tid] - gh; sse[1] = part[tid]; }
    __syncthreads();
    int s = sse[0], e = sse[1];
    for (int i = s + tid; i < e; i += 256) {
        uint2 q = bk[i];
        int c8 = (q.x >> 16) & 255;
        atomicAdd(&sdeg[c8], __uint_as_float(q.y));
        atomicAdd(&scnt[c8], 1);
    }
    __syncthreads();
    int cnt = scnt[tid];
    part[tid] = cnt;
    __syncthreads();
    for (int off = 1; off < 256; off <<= 1) {
        int t = (tid >= off) ? part[tid - off] : 0;
        __syncthreads();
        part[tid] += t;
        __syncthreads();
    }
    float d  = rsqrtf(sdeg[tid] + 1.0f);
    int   r0 = s + part[tid] - cnt;
    int gcol = b * BKB + tid;
    if (gcol < N) { dis[gcol] = d; rs[gcol] = r0; }
    if (b == 0 && tid == 0) rs[N] = E;
    cur[tid] = r0; sdis[tid] = d;
    __syncthreads();
    for (int i = s + tid; i < e; i += 256) {
        uint2 q = bk[i];
        int c8 = (q.x >> 16) & 255;
        unsigned r = q.x & 0xFFFFu;
        _Float16 wh = (_Float16)(__uint_as_float(q.y) * sdis[c8]);  // ew*dis[col]
        int pos = atomicAdd(&cur[c8], 1);
        edata[pos] = (r << 16) | (unsigned)__builtin_bit_cast(unsigned short, wh);
    }
}

// ------------------------------------------------- MFMA fp16 GEMM (layer1), dis epilogue
// out[r] = dis[r] * (A[r] @ W)  stored fp16.
__global__ __launch_bounds__(256) void k_gemm1(const float* __restrict__ A,
                                               const _Float16* __restrict__ Wt,
                                               const float* __restrict__ dis,
                                               _Float16* __restrict__ out, int M) {
    constexpr int NCOL = 128, AS = 136;
    __shared__ _Float16 Ah[64 * AS];
    __shared__ _Float16 Wh[NCOL * AS];

    int tid  = threadIdx.x;
    int row0 = blockIdx.x * 64;
#pragma unroll
    for (int q = 0; q < 8; q++) {
        int idx = tid + 256 * q;
        int r = idx >> 5, c4 = (idx & 31) * 4;
        float4 v = ld4(A + (size_t)(row0 + r) * K128 + c4);
        sth4(&Ah[r * AS + c4], v);
    }
#pragma unroll
    for (int q = 0; q < NCOL / 16; q++) {
        int idx = tid + 256 * q;
        int n = idx >> 4, c8 = (idx & 15) * 8;
        *(half8*)&Wh[n * AS + c8] = *(const half8*)(Wt + n * K128 + c8);
    }
    __syncthreads();

    int lane = tid & 63, wv = tid >> 6, m = lane & 15, quad = lane >> 4;
    f32x4 acc[NCOL / 16];
#pragma unroll
    for (int ct = 0; ct < NCOL / 16; ct++) acc[ct] = (f32x4){0.f, 0.f, 0.f, 0.f};
#pragma unroll
    for (int kt = 0; kt < 4; kt++) {
        half8 af = *(const half8*)&Ah[(wv * 16 + m) * AS + kt * 32 + quad * 8];
#pragma unroll
        for (int ct = 0; ct < NCOL / 16; ct++) {
            half8 bf = *(const half8*)&Wh[(ct * 16 + m) * AS + kt * 32 + quad * 8];
            acc[ct] = __builtin_amdgcn_mfma_f32_16x16x32_f16(af, bf, acc[ct], 0, 0, 0);
        }
    }
    float d[4];
#pragma unroll
    for (int r = 0; r < 4; r++) d[r] = dis[row0 + wv * 16 + quad * 4 + r];
#pragma unroll
    for (int ct = 0; ct < NCOL / 16; ct++)
#pragma unroll
        for (int r = 0; r < 4; r++) {
            int grow = row0 + wv * 16 + quad * 4 + r;
            out[(size_t)grow * NCOL + ct * 16 + m] = (_Float16)(acc[ct][r] * d[r]);
        }
}

// ------------------------------------------------- fused agg(F=128) + gemm2 (MFMA)
// 16 nodes/block. Phase 1: gather h1 rows (relu) into LDS tile (h1 never hits
// memory). Phase 2: xw2[16x64] = dis * (h1_tile @ W2) via 16x16x32 MFMA,
// each wave one 16-col strip of the shared 16-row A-tile.
__global__ __launch_bounds__(256) void k_agg_gemm(const _Float16* __restrict__ xw,
                                                  const float* __restrict__ dis,
                                                  const unsigned* __restrict__ edata,
                                                  const int* __restrict__ rs,
                                                  const float* __restrict__ bias,
                                                  const _Float16* __restrict__ Wt2,
                                                  _Float16* __restrict__ xw2, int N) {
    constexpr int F = 128, AS = 136;
    __shared__ _Float16 Hs[16 * AS];
    __shared__ _Float16 Ws[64 * AS];

    int tid   = threadIdx.x;
    int node0 = blockIdx.x * 16;
    int nl    = tid >> 4;            // 0..15
    int node  = node0 + nl;
    int j8    = (tid & 15) * 8;

    // stage Wt2 (64 x 128 fp16)
#pragma unroll
    for (int q = 0; q < 4; q++) {
        int idx = tid + 256 * q;
        int n = idx >> 4, c8 = (idx & 15) * 8;
        *(half8*)&Ws[n * AS + c8] = *(const half8*)(Wt2 + n * K128 + c8);
    }

    // ---- phase 1: gather. 4 independent accumulators x 8 features.
    float a0[8], a1[8], a2[8], a3[8];
    {
        float dv = dis[node];
        half8 sv = *(const half8*)(xw + (size_t)node * F + j8);
        float4 bA = ld4(bias + j8), bB = ld4(bias + j8 + 4);
#pragma unroll
        for (int t = 0; t < 4; t++) { a0[t] = (float)sv[t] * dv + (&bA.x)[t];
                                      a0[t + 4] = (float)sv[t + 4] * dv + (&bB.x)[t]; }
#pragma unroll
        for (int t = 0; t < 8; t++) { a1[t] = 0.f; a2[t] = 0.f; a3[t] = 0.f; }
    }
    int s = rs[node], e = rs[node + 1];
    int j = s;
    for (; j + 4 <= e; j += 4) {
        unsigned q0 = edata[j + 0], q1 = edata[j + 1], q2 = edata[j + 2], q3 = edata[j + 3];
        half8 v0 = *(const half8*)(xw + (size_t)(q0 >> 16) * F + j8);
        half8 v1 = *(const half8*)(xw + (size_t)(q1 >> 16) * F + j8);
        half8 v2 = *(const half8*)(xw + (size_t)(q2 >> 16) * F + j8);
        half8 v3 = *(const half8*)(xw + (size_t)(q3 >> 16) * F + j8);
        float n0 = unpack_w(q0), n1 = unpack_w(q1), n2 = unpack_w(q2), n3 = unpack_w(q3);
#pragma unroll
        for (int t = 0; t < 8; t++) {
            a0[t] += n0 * (float)v0[t];
            a1[t] += n1 * (float)v1[t];
            a2[t] += n2 * (float)v2[t];
            a3[t] += n3 * (float)v3[t];
        }
    }
    for (; j < e; j++) {
        unsigned q = edata[j];
        half8 v = *(const half8*)(xw + (size_t)(q >> 16) * F + j8);
        float nm = unpack_w(q);
#pragma unroll
        for (int t = 0; t < 8; t++) a0[t] += nm * (float)v[t];
    }
    half8 hv;
#pragma unroll
    for (int t = 0; t < 8; t++)
        hv[t] = (_Float16)fmaxf((a0[t] + a1[t]) + (a2[t] + a3[t]), 0.f);
    *(half8*)&Hs[nl * AS + j8] = hv;
    __syncthreads();

    // ---- phase 2: MFMA. wave wv -> cols wv*16..+15 of the 16-row tile.
    int lane = tid & 63, wv = tid >> 6, m = lane & 15, quad = lane >> 4;
    f32x4 acc = (f32x4){0.f, 0.f, 0.f, 0.f};
#pragma unroll
    for (int kt = 0; kt < 4; kt++) {
        half8 af = *(const half8*)&Hs[m * AS + kt * 32 + quad * 8];
        half8 bf = *(const half8*)&Ws[(wv * 16 + m) * AS + kt * 32 + quad * 8];
        acc = __builtin_amdgcn_mfma_f32_16x16x32_f16(af, bf, acc, 0, 0, 0);
    }
#pragma unroll
    for (int r = 0; r < 4; r++) {
        int gn = node0 + quad * 4 + r;
        xw2[(size_t)gn * 64 + wv * 16 + m] = (_Float16)(acc[r] * dis[gn]);
    }
}

// ------------------------------------------------- agg F=64 fused with mean-pool
__global__ __launch_bounds__(256) void k_agg_pool(const _Float16* __restrict__ xw,
                                                  const float* __restrict__ dis,
                                                  const unsigned* __restrict__ edata,
                                                  const int* __restrict__ rs,
                                                  const float* __restrict__ bias,
                                                  const int* __restrict__ batch,
                                                  float* __restrict__ g,
                                                  int* __restrict__ gcnt, int N) {
    constexpr int F = 64;
    __shared__ float T[16][F + 4];
    __shared__ int sb[16];
    int tid  = threadIdx.x;
    int base = blockIdx.x * 16;
    int nl   = tid >> 4;
    int node = base + nl;
    int j4   = (tid & 15) * 4;
    if (tid < 16) sb[tid] = batch[base + tid];

    float dv = dis[node];
    float4 self = ldh4(xw + (size_t)node * F + j4);
    float4 bv   = ld4(bias + j4);
    float4 a0 = make_float4(self.x * dv + bv.x, self.y * dv + bv.y,
                            self.z * dv + bv.z, self.w * dv + bv.w);
    float4 a1 = make_float4(0.f, 0.f, 0.f, 0.f);
    float4 a2 = a1, a3 = a1;
    int s = rs[node], e = rs[node + 1];
    int j = s;
    for (; j + 4 <= e; j += 4) {
        unsigned q0 = edata[j + 0], q1 = edata[j + 1], q2 = edata[j + 2], q3 = edata[j + 3];
        float4 v0 = ldh4(xw + (size_t)(q0 >> 16) * F + j4);
        float4 v1 = ldh4(xw + (size_t)(q1 >> 16) * F + j4);
        float4 v2 = ldh4(xw + (size_t)(q2 >> 16) * F + j4);
        float4 v3 = ldh4(xw + (size_t)(q3 >> 16) * F + j4);
        float n0 = unpack_w(q0), n1 = unpack_w(q1), n2 = unpack_w(q2), n3 = unpack_w(q3);
        a0.x += n0 * v0.x; a0.y += n0 * v0.y; a0.z += n0 * v0.z; a0.w += n0 * v0.w;
        a1.x += n1 * v1.x; a1.y += n1 * v1.y; a1.z += n1 * v1.z; a1.w += n1 * v1.w;
        a2.x += n2 * v2.x; a2.y += n2 * v2.y; a2.z += n2 * v2.z; a2.w += n2 * v2.w;
        a3.x += n3 * v3.x; a3.y += n3 * v3.y; a3.z += n3 * v3.z; a3.w += n3 * v3.w;
    }
    for (; j < e; j++) {
        unsigned q = edata[j];
        float nm = unpack_w(q);
        float4 v = ldh4(xw + (size_t)(q >> 16) * F + j4);
        a0.x += nm * v.x; a0.y += nm * v.y; a0.z += nm * v.z; a0.w += nm * v.w;
    }
    T[nl][j4 + 0] = fmaxf((a0.x + a1.x) + (a2.x + a3.x), 0.f);
    T[nl][j4 + 1] = fmaxf((a0.y + a1.y) + (a2.y + a3.y), 0.f);
    T[nl][j4 + 2] = fmaxf((a0.z + a1.z) + (a2.z + a3.z), 0.f);
    T[nl][j4 + 3] = fmaxf((a0.w + a1.w) + (a2.w + a3.w), 0.f);
    __syncthreads();
    if (tid < 64) {
        int f = tid;
        float run = 0.f;
        int cur = -1, cnt = 0;
        for (int k = 0; k < 16; k++) {
            int b = sb[k];
            if (b != cur) {
                if (cur >= 0) {
                    atomicAdd(&g[cur * 64 + f], run);
                    if (f == 0) atomicAdd(&gcnt[cur], cnt);
                }
                cur = b; run = 0.f; cnt = 0;
            }
            run += T[k][f];
            cnt++;
        }
        atomicAdd(&g[cur * 64 + f], run);
        if (f == 0) atomicAdd(&gcnt[cur], cnt);
    }
}

// ------------------------------------------------- FC: out[NG,FLAT] = (g/cnt) @ Wfc + bfc
__global__ __launch_bounds__(256) void k_fc(const float* __restrict__ g,
                                            const int* __restrict__ gcnt,
                                            const float* __restrict__ Wfc,
                                            const float* __restrict__ bfc,
                                            float* __restrict__ out) {
    __shared__ float gs[64];
    int i = blockIdx.y;
    int j = blockIdx.x * blockDim.x + threadIdx.x;
    if (threadIdx.x < 64) {
        float c = (float)gcnt[i];
        gs[threadIdx.x] = g[i * 64 + threadIdx.x] / fmaxf(c, 1.0f);
    }
    __syncthreads();
    if (j >= FLAT) return;
    float acc = bfc[j];
#pragma unroll 8
    for (int k = 0; k < 64; k++) acc += gs[k] * Wfc[k * FLAT + j];
    out[(size_t)i * FLAT + j] = acc;
}

// ================================================================ launcher
extern "C" void kernel_launch(void* const* d_in, const int* in_sizes, int n_in,
                              void* d_out, int out_size, void* d_ws, size_t ws_size,
                              hipStream_t stream) {
    const float* x    = (const float*)d_in[0];
    const int*   ei   = (const int*)d_in[1];
    const float* ew   = (const float*)d_in[2];
    const int*   batch= (const int*)d_in[3];
    const float* W1   = (const float*)d_in[4];
    const float* b1   = (const float*)d_in[5];
    const float* W2   = (const float*)d_in[6];
    const float* b2   = (const float*)d_in[7];
    const float* Wfc  = (const float*)d_in[8];
    const float* bfc  = (const float*)d_in[9];
    float* out = (float*)d_out;

    const int N = in_sizes[0] / K128;   // 40000
    const int E = in_sizes[2];          // 640000
    const int* row = ei;
    const int* col = ei + E;
    const int nbk = (N + BKB - 1) / BKB;   // 157 buckets
    const int neb = (E + 1023) / 1024;     // edge-chunk blocks

    // ---- workspace carve (256B aligned)
    char* p = (char*)d_ws;
    auto alloc = [&](size_t bytes) -> void* {
        void* r = (void*)p;
        p += (bytes + 255) & ~(size_t)255;
        return r;
    };
    float*     dis   = (float*)    alloc((size_t)N * 4);
    int*       rs    = (int*)      alloc((size_t)(N + 1) * 4);
    uint2*     bk    = (uint2*)    alloc((size_t)E * 8);
    unsigned*  edata = (unsigned*) alloc((size_t)E * 4);
    _Float16*  xw1   = (_Float16*) alloc((size_t)N * 128 * 2);
    _Float16*  xw2   = (_Float16*) alloc((size_t)N * 64 * 2);
    _Float16*  Wt1   = (_Float16*) alloc((size_t)128 * 128 * 2);
    _Float16*  Wt2   = (_Float16*) alloc((size_t)64 * 128 * 2);
    float*     g     = (float*)    alloc(64 * 64 * 4);
    int*       gcnt  = (int*)      alloc(64 * 4);
    int*       bhist = (int*)      alloc(BKB * 4);
    int*       bcur  = (int*)      alloc(BKB * 4);

    // ---- 8 dispatches total
    k_init     <<<96,  256, 0, stream>>>(bhist, bcur, g, gcnt, W1, W2, Wt1, Wt2);
    k_bhist    <<<neb, 256, 0, stream>>>(col, bhist, E, nbk);
    k_bucket   <<<neb, 256, 0, stream>>>(row, col, ew, bhist, bcur, bk, E, nbk);
    k_colsedata<<<nbk, 256, 0, stream>>>(bk, bhist, dis, rs, edata, N, E, nbk);

    k_gemm1    <<<N / 64, 256, 0, stream>>>(x, Wt1, dis, xw1, N);
    k_agg_gemm <<<N / 16, 256, 0, stream>>>(xw1, dis, edata, rs, b1, Wt2, xw2, N);
    k_agg_pool <<<N / 16, 256, 0, stream>>>(xw2, dis, edata, rs, b2, batch, g, gcnt, N);

    dim3 fcg((FLAT + 255) / 256, NG);
    k_fc<<<fcg, 256, 0, stream>>>(g, gcnt, Wfc, bfc, out);
}